// Round 15
// baseline (373.659 us; speedup 1.0000x reference)
//
#include <hip/hip_runtime.h>
#include <stdint.h>

#define TPB 1024
#define NL 4

typedef _Float16 f16;
typedef _Float16 half2v __attribute__((ext_vector_type(2)));
typedef _Float16 f16x8 __attribute__((ext_vector_type(8)));
typedef float f32x4 __attribute__((ext_vector_type(4)));
typedef uint32_t u32x2 __attribute__((ext_vector_type(2)));
typedef uint32_t u32x4 __attribute__((ext_vector_type(4)));

// X2 u32 index for row r, u32-col c: 16B-block XOR swizzle (block ^= r&7).
#define XIU(r, c) ((r) * 32 + (((((c) >> 2) ^ ((r) & 7))) << 2) + ((c) & 3))

static __device__ __forceinline__ uint32_t packh2(float a, float b) {
  half2v h;
  h.x = (_Float16)a;
  h.y = (_Float16)b;
  return __builtin_bit_cast(uint32_t, h);
}
static __device__ __forceinline__ float2 unpackh2(uint32_t u) {
  half2v h = __builtin_bit_cast(half2v, u);
  return make_float2((float)h.x, (float)h.y);
}

__global__ void pack_weights_kernel(const float* __restrict__ ff1_w,
                                    const float* __restrict__ ff2_w,
                                    f16* __restrict__ w1h,
                                    f16* __restrict__ w2h,
                                    float* __restrict__ petab) {
  int idx = blockIdx.x * blockDim.x + threadIdx.x;
  if (idx < 16384) {
    w1h[idx] = (f16)ff1_w[idx];
  } else if (idx < 32768) {
    w2h[idx - 16384] = (f16)ff2_w[idx - 16384];
  } else if (petab != nullptr && idx < 32768 + 64000) {
    int j = idx - 32768;
    int s = j >> 6, d = j & 63;
    float div = exp2f(-0.4152410118609203f * (float)(d >> 1));
    float ang = (float)s * div;
    petab[j] = (d & 1) ? cosf(ang) : sinf(ang);
  }
}

// R15 (= R14 resubmitted; R14's run was an infra failure, no kernel signal).
// R11's silicon-verified wave-independent FF + explicit occupancy pinning.
// The default regalloc budget targets 8 waves/EU (64 VGPR) and ignores that
// our 160 KB LDS already caps residency at 1 block = 4 waves/EU;
// __launch_bounds__(1024,4) + amdgpu_waves_per_eu(4,4) raise the legal budget
// to 512/4 = 128 VGPRs. The LICM-hoisted W1+W2 tiles (64 regs) + ~30
// transients then fit without spill (R11 spilled 282 MB at budget 64) and
// without R12's latency-serializing pointer laundering. Wave-independent FF:
// no cross-wave H, no LN2 pass, no pad-zeroing, 3 barriers/layer (R13: 12).
__global__ __launch_bounds__(TPB, 4)
__attribute__((amdgpu_waves_per_eu(4, 4))) void aat_kernel(
    const int* __restrict__ tokens, const float* __restrict__ emb,
    const float* __restrict__ lin_w, const float* __restrict__ lin_b,
    const float* __restrict__ ff1_b, const float* __restrict__ ff2_b,
    const float* __restrict__ n1_g, const float* __restrict__ n1_b,
    const float* __restrict__ n2_g, const float* __restrict__ n2_b,
    const float* __restrict__ out_w, const float* __restrict__ out_b,
    const f16* __restrict__ w1h, const f16* __restrict__ w2h,
    const float* __restrict__ petab, float* __restrict__ out) {
  __shared__ uint32_t X2[1000 * 32];      // 128000 B, swizzled rows (f16 pairs)
  __shared__ uint32_t Hreg[16 * 512];     // 32768 B: per-wave H [16][32] / avg redbuf
  __shared__ float avgbuf[64];
  __shared__ __align__(8) float attnbuf[64];

  const int t = threadIdx.x;
  const int b = blockIdx.x;
  const int lane = t & 63;
  const int wv = t >> 6;                  // 0..15
  const bool valid = (t < 1000);
  float* redbuf = (float*)Hreg;           // [32][64] f32 during avg phase

  // ---------------- embed * sqrt(d) + positional encoding -> X2 ----------------
  if (valid) {
    int tok = tokens[b * 1000 + t];
    const float4* ev = (const float4*)(emb + (size_t)tok * 64);
    const int r7 = t & 7;
    if (petab != nullptr) {
      const float4* pv = (const float4*)(petab + (size_t)t * 64);
      #pragma unroll
      for (int q = 0; q < 8; q++) {
        float4 v0 = ev[2 * q], v1 = ev[2 * q + 1];
        float4 p0 = pv[2 * q], p1 = pv[2 * q + 1];
        u32x4 w;
        w[0] = packh2(fmaf(v0.x, 8.f, p0.x), fmaf(v0.y, 8.f, p0.y));
        w[1] = packh2(fmaf(v0.z, 8.f, p0.z), fmaf(v0.w, 8.f, p0.w));
        w[2] = packh2(fmaf(v1.x, 8.f, p1.x), fmaf(v1.y, 8.f, p1.y));
        w[3] = packh2(fmaf(v1.z, 8.f, p1.z), fmaf(v1.w, 8.f, p1.w));
        *(u32x4*)(&X2[t * 32 + ((q ^ r7) << 2)]) = w;
      }
    } else {
      float fs = (float)t;
      #pragma unroll
      for (int q = 0; q < 8; q++) {
        float4 v0 = ev[2 * q], v1 = ev[2 * q + 1];
        float d0 = exp2f(-0.4152410118609203f * (float)(4 * q));
        float d1 = exp2f(-0.4152410118609203f * (float)(4 * q + 1));
        float d2 = exp2f(-0.4152410118609203f * (float)(4 * q + 2));
        float d3 = exp2f(-0.4152410118609203f * (float)(4 * q + 3));
        u32x4 w;
        w[0] = packh2(fmaf(v0.x, 8.f, sinf(fs * d0)), fmaf(v0.y, 8.f, cosf(fs * d0)));
        w[1] = packh2(fmaf(v0.z, 8.f, sinf(fs * d1)), fmaf(v0.w, 8.f, cosf(fs * d1)));
        w[2] = packh2(fmaf(v1.x, 8.f, sinf(fs * d2)), fmaf(v1.y, 8.f, cosf(fs * d2)));
        w[3] = packh2(fmaf(v1.z, 8.f, sinf(fs * d3)), fmaf(v1.w, 8.f, cosf(fs * d3)));
        *(u32x4*)(&X2[t * 32 + ((q ^ r7) << 2)]) = w;
      }
    }
  }
  __syncthreads();

  const int l15 = lane & 15;
  const int g4 = lane >> 4;               // 0..3
  const int e7 = l15 & 7;                 // == (FF row s) & 7 for this lane
  uint32_t* hw = Hreg + wv * 512;         // per-wave H slice [16][32], swizzled

  #pragma unroll 1
  for (int l = 0; l < NL; l++) {
    const float* n1g = n1_g + l * 64;
    const float* n1b = n1_b + l * 64;
    const float* n2gl = n2_g + l * 64;
    const float* n2bl = n2_b + l * 64;
    const float* f1b = ff1_b + l * 64;
    const float* f2b = ff2_b + l * 64;
    const f16* w1l = w1h + l * 4096;
    const f16* w2l = w2h + l * 4096;

    // ------- avg over sequence: column-parallel partials into redbuf -------
    {
      int cp = t & 31, rg = t >> 5;
      float s0 = 0.f, s1 = 0.f;
      for (int r = rg; r < 1000; r += 32) {
        float2 v = unpackh2(X2[XIU(r, cp)]);
        s0 += v.x;
        s1 += v.y;
      }
      redbuf[rg * 64 + 2 * cp] = s0;
      redbuf[rg * 64 + 2 * cp + 1] = s1;
    }
    __syncthreads();                       // barrier 1: redbuf complete
    if (t < 64) {
      float ssum = 0.f;
      #pragma unroll
      for (int w = 0; w < 32; w++) ssum += redbuf[w * 64 + t];
      avgbuf[t] = ssum * 1e-3f;
    }
    if (t < 64) {  // attn[o] = lin_b[o] + sum_d avg[d]*lin_w[o][d] (wave0-local)
      const float* wr = lin_w + (size_t)(l * 64 + t) * 64;
      float a0 = lin_b[l * 64 + t], a1 = 0.f, a2 = 0.f, a3 = 0.f;
      #pragma unroll
      for (int d = 0; d < 64; d += 4) {
        a0 += avgbuf[d] * wr[d];
        a1 += avgbuf[d + 1] * wr[d + 1];
        a2 += avgbuf[d + 2] * wr[d + 2];
        a3 += avgbuf[d + 3] * wr[d + 3];
      }
      attnbuf[t] = (a0 + a1) + (a2 + a3);
    }
    __syncthreads();                       // barrier 2: attnbuf visible to all

    // ---------------- LN1 (thread t = row t): Y overwrites X2 ----------------
    if (valid) {
      const float2* at2 = (const float2*)attnbuf;
      const int r7 = t & 7;
      float m0 = 0.f, q0 = 0.f;
      #pragma unroll
      for (int q = 0; q < 8; q++) {
        u32x4 w = *(const u32x4*)(&X2[t * 32 + ((q ^ r7) << 2)]);
        #pragma unroll
        for (int j = 0; j < 4; j++) {
          float2 xv = unpackh2(w[j]);
          float2 at = at2[q * 4 + j];
          float a0 = xv.x + at.x, a1 = xv.y + at.y;
          m0 += a0 + a1;
          q0 = fmaf(a0, a0, q0);
          q0 = fmaf(a1, a1, q0);
        }
      }
      float mu = m0 * (1.0f / 64.0f);
      float var = q0 * (1.0f / 64.0f) - mu * mu;
      float rs = rsqrtf(var + 1e-5f);
      #pragma unroll
      for (int q = 0; q < 8; q++) {
        u32x4 w = *(const u32x4*)(&X2[t * 32 + ((q ^ r7) << 2)]);
        u32x4 o;
        #pragma unroll
        for (int j = 0; j < 4; j++) {
          float2 xv = unpackh2(w[j]);
          float2 at = at2[q * 4 + j];
          int d = (q * 4 + j) * 2;
          float a0 = xv.x + at.x, a1 = xv.y + at.y;
          o[j] = packh2(fmaf((a0 - mu) * rs, n1g[d], n1b[d]),
                        fmaf((a1 - mu) * rs, n1g[d + 1], n1b[d + 1]));
        }
        *(u32x4*)(&X2[t * 32 + ((q ^ r7) << 2)]) = o;
      }
    }
    // no barrier: each wave's FF touches only its own 64 rows.

    // ---------------- FF: wave-private, swapped MFMA ----------------
    #pragma unroll 1
    for (int rg = 0; rg < 4; rg++) {
      const int s = wv * 64 + rg * 16 + l15;   // this lane's seq row (B-col)
      const int sbase = s * 32;                 // (s>=1000: OOB reads land in
                                                // Hreg, harmless; writes masked)
      // B1 = Y^T fragments: two b128 reads
      u32x4 b1q0 = *(const u32x4*)(&X2[sbase + ((g4 ^ e7) << 2)]);
      u32x4 b1q1 = *(const u32x4*)(&X2[sbase + (((4 + g4) ^ e7) << 2)]);
      f16x8 B1k0 = __builtin_bit_cast(f16x8, b1q0);
      f16x8 B1k1 = __builtin_bit_cast(f16x8, b1q1);

      // ---- mm1: H^T = W1 * Y^T, 4 tiles, write H to per-wave LDS (b64) ----
#define MM1T(OT) { \
      const f16* ap = w1l + (16 * (OT) + l15) * 64 + 8 * g4; \
      f16x8 A0 = *(const f16x8*)(ap); \
      f16x8 A1 = *(const f16x8*)(ap + 32); \
      f32x4 acc = *(const f32x4*)(f1b + 16 * (OT) + 4 * g4); \
      acc = __builtin_amdgcn_mfma_f32_16x16x32_f16(A0, B1k0, acc, 0, 0, 0); \
      acc = __builtin_amdgcn_mfma_f32_16x16x32_f16(A1, B1k1, acc, 0, 0, 0); \
      u32x2 hp; \
      hp[0] = packh2(fmaxf(acc[0], 0.f), fmaxf(acc[1], 0.f)); \
      hp[1] = packh2(fmaxf(acc[2], 0.f), fmaxf(acc[3], 0.f)); \
      *(u32x2*)(&hw[l15 * 32 + (((2 * (OT) + (g4 >> 1)) ^ e7) << 2) + 2 * (g4 & 1)]) = hp; }
      MM1T(0)
      MM1T(1)
      MM1T(2)
      MM1T(3)
#undef MM1T

      // B2 = H fragments: two b128 reads (same-wave data)
      u32x4 h0 = *(const u32x4*)(&hw[l15 * 32 + ((g4 ^ e7) << 2)]);
      u32x4 h1 = *(const u32x4*)(&hw[l15 * 32 + (((4 + g4) ^ e7) << 2)]);
      f16x8 B2k0 = __builtin_bit_cast(f16x8, h0);
      f16x8 B2k1 = __builtin_bit_cast(f16x8, h1);

      // ---- mm2: T^T = W2 * H + b2 + Y, tile-serial, T packed to 8 u32 ----
      float sum = 0.f, sq = 0.f;
      u32x2 tp0, tp1, tp2, tp3;
#define MM2T(OT, TP) { \
      const f16* ap = w2l + (16 * (OT) + l15) * 64 + 8 * g4; \
      f16x8 A0 = *(const f16x8*)(ap); \
      f16x8 A1 = *(const f16x8*)(ap + 32); \
      u32x2 ry = *(const u32x2*)(&X2[sbase + (((2 * (OT) + (g4 >> 1)) ^ e7) << 2) + 2 * (g4 & 1)]); \
      float2 r0 = unpackh2(ry[0]), r1 = unpackh2(ry[1]); \
      f32x4 acc = *(const f32x4*)(f2b + 16 * (OT) + 4 * g4); \
      acc[0] += r0.x; acc[1] += r0.y; acc[2] += r1.x; acc[3] += r1.y; \
      acc = __builtin_amdgcn_mfma_f32_16x16x32_f16(A0, B2k0, acc, 0, 0, 0); \
      acc = __builtin_amdgcn_mfma_f32_16x16x32_f16(A1, B2k1, acc, 0, 0, 0); \
      sum += (acc[0] + acc[1]) + (acc[2] + acc[3]); \
      sq = fmaf(acc[0], acc[0], sq); sq = fmaf(acc[1], acc[1], sq); \
      sq = fmaf(acc[2], acc[2], sq); sq = fmaf(acc[3], acc[3], sq); \
      TP[0] = packh2(acc[0], acc[1]); TP[1] = packh2(acc[2], acc[3]); }
      MM2T(0, tp0)
      MM2T(1, tp1)
      MM2T(2, tp2)
      MM2T(3, tp3)
#undef MM2T

      // ---- in-register LN2: row sums across the 4 g4-lanes of row s ----
      sum += __shfl_xor(sum, 16, 64);
      sum += __shfl_xor(sum, 32, 64);
      sq += __shfl_xor(sq, 16, 64);
      sq += __shfl_xor(sq, 32, 64);
      float mu2 = sum * (1.0f / 64.0f);
      float var2 = sq * (1.0f / 64.0f) - mu2 * mu2;
      float rs2 = rsqrtf(var2 + 1e-5f);
      if (s < 1000) {
#define WBT(OT, TP) { \
        f32x4 gg = *(const f32x4*)(n2gl + 16 * (OT) + 4 * g4); \
        f32x4 bb = *(const f32x4*)(n2bl + 16 * (OT) + 4 * g4); \
        float2 v0 = unpackh2(TP[0]), v1 = unpackh2(TP[1]); \
        u32x2 xw; \
        xw[0] = packh2(fmaf((v0.x - mu2) * rs2, gg[0], bb[0]), \
                       fmaf((v0.y - mu2) * rs2, gg[1], bb[1])); \
        xw[1] = packh2(fmaf((v1.x - mu2) * rs2, gg[2], bb[2]), \
                       fmaf((v1.y - mu2) * rs2, gg[3], bb[3])); \
        *(u32x2*)(&X2[sbase + (((2 * (OT) + (g4 >> 1)) ^ e7) << 2) + 2 * (g4 & 1)]) = xw; }
        WBT(0, tp0) WBT(1, tp1) WBT(2, tp2) WBT(3, tp3)
#undef WBT
      }
    }
    __syncthreads();                       // barrier 3: layer complete
  }

  // ---------------- output projection [B,S,2] ----------------
  if (valid) {
    const int r7 = t & 7;
    float a0 = out_b[0], a1 = out_b[1];
    #pragma unroll
    for (int q = 0; q < 8; q++) {
      u32x4 w = *(const u32x4*)(&X2[t * 32 + ((q ^ r7) << 2)]);
      #pragma unroll
      for (int j = 0; j < 4; j++) {
        float2 xv = unpackh2(w[j]);
        int d = (q * 4 + j) * 2;
        a0 += xv.x * out_w[d] + xv.y * out_w[d + 1];
        a1 += xv.x * out_w[64 + d] + xv.y * out_w[64 + d + 1];
      }
    }
    *(float2*)(out + (size_t)(b * 1000 + t) * 2) = make_float2(a0, a1);
  }
}

extern "C" void kernel_launch(void* const* d_in, const int* in_sizes, int n_in,
                              void* d_out, int out_size, void* d_ws, size_t ws_size,
                              hipStream_t stream) {
  const int* tokens = (const int*)d_in[0];
  const float* emb = (const float*)d_in[1];
  const float* lin_w = (const float*)d_in[2];
  const float* lin_b = (const float*)d_in[3];
  const float* ff1_w = (const float*)d_in[4];
  const float* ff1_b = (const float*)d_in[5];
  const float* ff2_w = (const float*)d_in[6];
  const float* ff2_b = (const float*)d_in[7];
  const float* n1_g = (const float*)d_in[8];
  const float* n1_b = (const float*)d_in[9];
  const float* n2_g = (const float*)d_in[10];
  const float* n2_b = (const float*)d_in[11];
  const float* out_w = (const float*)d_in[12];
  const float* out_b = (const float*)d_in[13];
  float* out = (float*)d_out;

  f16* w1h = (f16*)d_ws;                         // 32 KiB
  f16* w2h = w1h + 16384;                        // 32 KiB
  float* petab = (float*)((char*)d_ws + 65536);  // 250 KiB (1000*64 f32)
  const size_t need = 65536 + 64000 * 4;
  const bool use_pe = (ws_size >= need);
  float* pe_arg = use_pe ? petab : nullptr;

  int pack_threads = 32768 + (use_pe ? 64000 : 0);
  int pack_blocks = (pack_threads + 255) / 256;
  pack_weights_kernel<<<pack_blocks, 256, 0, stream>>>(ff1_w, ff2_w, w1h, w2h, pe_arg);
  aat_kernel<<<512, TPB, 0, stream>>>(tokens, emb, lin_w, lin_b, ff1_b, ff2_b,
                                      n1_g, n1_b, n2_g, n2_b, out_w, out_b,
                                      w1h, w2h, pe_arg, out);
}

// Round 16
// 309.057 us; speedup vs baseline: 1.2090x; 1.2090x over previous
//
#include <hip/hip_runtime.h>
#include <stdint.h>

#define TPB 1024
#define NL 4

typedef _Float16 f16;
typedef _Float16 half2v __attribute__((ext_vector_type(2)));
typedef _Float16 f16x8 __attribute__((ext_vector_type(8)));
typedef float f32x4 __attribute__((ext_vector_type(4)));
typedef uint32_t u32x2 __attribute__((ext_vector_type(2)));
typedef uint32_t u32x4 __attribute__((ext_vector_type(4)));

// X2/Hb u32 index for row r, u32-col c: 16B-block XOR swizzle (block ^= r&7).
#define XIU(r, c) ((r) * 32 + (((((c) >> 2) ^ ((r) & 7))) << 2) + ((c) & 3))

static __device__ __forceinline__ uint32_t packh2(float a, float b) {
  half2v h;
  h.x = (_Float16)a;
  h.y = (_Float16)b;
  return __builtin_bit_cast(uint32_t, h);
}
static __device__ __forceinline__ float2 unpackh2(uint32_t u) {
  half2v h = __builtin_bit_cast(half2v, u);
  return make_float2((float)h.x, (float)h.y);
}

__global__ void pack_weights_kernel(const float* __restrict__ ff1_w,
                                    const float* __restrict__ ff2_w,
                                    f16* __restrict__ w1h,
                                    f16* __restrict__ w2h,
                                    float* __restrict__ petab) {
  int idx = blockIdx.x * blockDim.x + threadIdx.x;
  if (idx < 16384) {
    w1h[idx] = (f16)ff1_w[idx];
  } else if (idx < 32768) {
    w2h[idx - 16384] = (f16)ff2_w[idx - 16384];
  } else if (petab != nullptr && idx < 32768 + 64000) {
    int j = idx - 32768;
    int s = j >> 6, d = j & 63;
    float div = exp2f(-0.4152410118609203f * (float)(d >> 1));
    float ang = (float)s * div;
    petab[j] = (d & 1) ? cosf(ang) : sinf(ang);
  }
}

// R16 = R13 (banked 213us; spill-free at the backend's hard 64-VGPR choice --
// R9/R11/R15 proved no attribute raises it, so every phase must fit ~60 live)
// + two conservative upgrades:
// 1. Software-pipelined FF: 8 chunks x 128 rows, dual 16KB H buffers (same
//    32KB footprint). Each inter-barrier phase = mm1(c) || mm2(c-1): two
//    independent streams per wave hide LDS/MFMA latency; sched_barrier(0)
//    between halves caps pressure at R13's per-section level.
// 2. Single-pass LN1/LN2: row's 8 x u32x4 held in registers between stats
//    and normalize (~45 live, the always-promoting size class) -- halves LN
//    LDS reads + address math.
__global__ __launch_bounds__(TPB) void aat_kernel(
    const int* __restrict__ tokens, const float* __restrict__ emb,
    const float* __restrict__ lin_w, const float* __restrict__ lin_b,
    const float* __restrict__ ff1_b, const float* __restrict__ ff2_b,
    const float* __restrict__ n1_g, const float* __restrict__ n1_b,
    const float* __restrict__ n2_g, const float* __restrict__ n2_b,
    const float* __restrict__ out_w, const float* __restrict__ out_b,
    const f16* __restrict__ w1h, const f16* __restrict__ w2h,
    const float* __restrict__ petab, float* __restrict__ out) {
  __shared__ __align__(16) uint32_t X2[1024 * 32];  // 131072 B
  __shared__ __align__(16) uint32_t Hb[2 * 4096];   // 32768 B: 2 H bufs / redbuf

  const int t = threadIdx.x;
  const int b = blockIdx.x;
  const int lane = t & 63;
  const int wv = t >> 6;                  // 0..15
  const bool valid = (t < 1000);
  float* redbuf = (float*)Hb;             // [32][64] f32 (avg phase)
  float* avgbuf = (float*)(Hb + 2048);    // 64 f32
  float* attnbuf = (float*)(Hb + 2112);   // 64 f32, 8B-aligned

  // ---------------- embed * sqrt(d) + positional encoding -> X2 ----------------
  if (valid) {
    int tok = tokens[b * 1000 + t];
    const float4* ev = (const float4*)(emb + (size_t)tok * 64);
    const int r7 = t & 7;
    if (petab != nullptr) {
      const float4* pv = (const float4*)(petab + (size_t)t * 64);
      #pragma unroll
      for (int q = 0; q < 8; q++) {
        float4 v0 = ev[2 * q], v1 = ev[2 * q + 1];
        float4 p0 = pv[2 * q], p1 = pv[2 * q + 1];
        u32x4 w;
        w[0] = packh2(fmaf(v0.x, 8.f, p0.x), fmaf(v0.y, 8.f, p0.y));
        w[1] = packh2(fmaf(v0.z, 8.f, p0.z), fmaf(v0.w, 8.f, p0.w));
        w[2] = packh2(fmaf(v1.x, 8.f, p1.x), fmaf(v1.y, 8.f, p1.y));
        w[3] = packh2(fmaf(v1.z, 8.f, p1.z), fmaf(v1.w, 8.f, p1.w));
        *(u32x4*)(&X2[t * 32 + ((q ^ r7) << 2)]) = w;
      }
    } else {
      float fs = (float)t;
      #pragma unroll
      for (int q = 0; q < 8; q++) {
        float4 v0 = ev[2 * q], v1 = ev[2 * q + 1];
        float d0 = exp2f(-0.4152410118609203f * (float)(4 * q));
        float d1 = exp2f(-0.4152410118609203f * (float)(4 * q + 1));
        float d2 = exp2f(-0.4152410118609203f * (float)(4 * q + 2));
        float d3 = exp2f(-0.4152410118609203f * (float)(4 * q + 3));
        u32x4 w;
        w[0] = packh2(fmaf(v0.x, 8.f, sinf(fs * d0)), fmaf(v0.y, 8.f, cosf(fs * d0)));
        w[1] = packh2(fmaf(v0.z, 8.f, sinf(fs * d1)), fmaf(v0.w, 8.f, cosf(fs * d1)));
        w[2] = packh2(fmaf(v1.x, 8.f, sinf(fs * d2)), fmaf(v1.y, 8.f, cosf(fs * d2)));
        w[3] = packh2(fmaf(v1.z, 8.f, sinf(fs * d3)), fmaf(v1.w, 8.f, cosf(fs * d3)));
        *(u32x4*)(&X2[t * 32 + ((q ^ r7) << 2)]) = w;
      }
    }
  } else {
    #pragma unroll
    for (int c = 0; c < 32; c += 4)
      *(u32x4*)(&X2[t * 32 + c]) = (u32x4){0u, 0u, 0u, 0u};  // pad rows zero
  }
  __syncthreads();

  const int l15 = lane & 15;
  const int g4 = lane >> 4;               // 0..3
  const int e7 = l15 & 7;                 // (row)&7 for all FF rows of this lane
  const int nt = wv & 3;                  // output-tile (16 cols of W1/W2)
  const int mr = wv >> 2;                 // row-group within a 128-row chunk
  const int cw = 8 * nt + 2 * g4;         // u32-col base of this lane's 4 outputs
  const int cswz = (((cw >> 2) ^ e7) << 2) + (cw & 3);  // swizzled col offset

  #pragma unroll 1
  for (int l = 0; l < NL; l++) {
    const float* n1g = n1_g + l * 64;
    const float* n1b = n1_b + l * 64;
    const float* n2gl = n2_g + l * 64;
    const float* n2bl = n2_b + l * 64;

    // Per-wave weight tile (LICM hoists to layer scope: 24 VGPRs, fits)
    const f16* w1p = w1h + l * 4096 + (16 * nt + l15) * 64 + 8 * g4;
    f16x8 A10 = *(const f16x8*)(w1p);
    f16x8 A11 = *(const f16x8*)(w1p + 32);
    const f16* w2p = w2h + l * 4096 + (16 * nt + l15) * 64 + 8 * g4;
    f16x8 A20 = *(const f16x8*)(w2p);
    f16x8 A21 = *(const f16x8*)(w2p + 32);
    f32x4 bias1 = *(const f32x4*)(ff1_b + l * 64 + 16 * nt + 4 * g4);
    f32x4 bias2 = *(const f32x4*)(ff2_b + l * 64 + 16 * nt + 4 * g4);

    // ------- avg over sequence: column-parallel partials into redbuf -------
    {
      int cp = t & 31, rg = t >> 5;
      float s0 = 0.f, s1 = 0.f;
      for (int r = rg; r < 1000; r += 32) {
        float2 v = unpackh2(X2[XIU(r, cp)]);
        s0 += v.x;
        s1 += v.y;
      }
      redbuf[rg * 64 + 2 * cp] = s0;
      redbuf[rg * 64 + 2 * cp + 1] = s1;
    }
    __syncthreads();                       // bar 1
    if (t < 64) {
      float ssum = 0.f;
      #pragma unroll
      for (int w = 0; w < 32; w++) ssum += redbuf[w * 64 + t];
      avgbuf[t] = ssum * 1e-3f;
    }
    if (t < 64) {  // attn[o] = lin_b[o] + sum_d avg[d]*lin_w[o][d]
      const float* wr = lin_w + (size_t)(l * 64 + t) * 64;
      float a0 = lin_b[l * 64 + t], a1 = 0.f, a2 = 0.f, a3 = 0.f;
      #pragma unroll
      for (int d = 0; d < 64; d += 4) {
        a0 += avgbuf[d] * wr[d];
        a1 += avgbuf[d + 1] * wr[d + 1];
        a2 += avgbuf[d + 2] * wr[d + 2];
        a3 += avgbuf[d + 3] * wr[d + 3];
      }
      attnbuf[t] = (a0 + a1) + (a2 + a3);
    }
    __syncthreads();                       // bar 2

    // ------- LN1 (thread t = row t), single pass: row held in registers -------
    if (valid) {
      const float2* at2 = (const float2*)attnbuf;
      const int r7 = t & 7;
      u32x4 wq0 = *(const u32x4*)(&X2[t * 32 + ((0 ^ r7) << 2)]);
      u32x4 wq1 = *(const u32x4*)(&X2[t * 32 + ((1 ^ r7) << 2)]);
      u32x4 wq2 = *(const u32x4*)(&X2[t * 32 + ((2 ^ r7) << 2)]);
      u32x4 wq3 = *(const u32x4*)(&X2[t * 32 + ((3 ^ r7) << 2)]);
      u32x4 wq4 = *(const u32x4*)(&X2[t * 32 + ((4 ^ r7) << 2)]);
      u32x4 wq5 = *(const u32x4*)(&X2[t * 32 + ((5 ^ r7) << 2)]);
      u32x4 wq6 = *(const u32x4*)(&X2[t * 32 + ((6 ^ r7) << 2)]);
      u32x4 wq7 = *(const u32x4*)(&X2[t * 32 + ((7 ^ r7) << 2)]);
      float m0 = 0.f, q0 = 0.f;
#define LN1S(WQ, Q) { _Pragma("unroll") for (int j = 0; j < 4; j++) { \
      float2 xv = unpackh2(WQ[j]); float2 at = at2[(Q) * 4 + j]; \
      float a0 = xv.x + at.x, a1 = xv.y + at.y; \
      m0 += a0 + a1; q0 = fmaf(a0, a0, q0); q0 = fmaf(a1, a1, q0); } }
      LN1S(wq0, 0) LN1S(wq1, 1) LN1S(wq2, 2) LN1S(wq3, 3)
      LN1S(wq4, 4) LN1S(wq5, 5) LN1S(wq6, 6) LN1S(wq7, 7)
#undef LN1S
      float mu = m0 * (1.0f / 64.0f);
      float var = q0 * (1.0f / 64.0f) - mu * mu;
      float rs = rsqrtf(var + 1e-5f);
#define LN1N(WQ, Q) { u32x4 o; _Pragma("unroll") for (int j = 0; j < 4; j++) { \
      float2 xv = unpackh2(WQ[j]); float2 at = at2[(Q) * 4 + j]; \
      int d = ((Q) * 4 + j) * 2; \
      float a0 = xv.x + at.x, a1 = xv.y + at.y; \
      o[j] = packh2(fmaf((a0 - mu) * rs, n1g[d], n1b[d]), \
                    fmaf((a1 - mu) * rs, n1g[d + 1], n1b[d + 1])); } \
      *(u32x4*)(&X2[t * 32 + (((Q) ^ r7) << 2)]) = o; }
      LN1N(wq0, 0) LN1N(wq1, 1) LN1N(wq2, 2) LN1N(wq3, 3)
      LN1N(wq4, 4) LN1N(wq5, 5) LN1N(wq6, 6) LN1N(wq7, 7)
#undef LN1N
    }
    __syncthreads();                       // bar 3: Y visible to FF waves

    // ------- FF: 8 chunks of 128 rows, software-pipelined (dual H bufs) -------
#define MM1C(C, HB) { _Pragma("unroll") for (int sb = 0; sb < 2; sb++) { \
    const int s = 128 * (C) + 32 * mr + 16 * sb + l15; \
    u32x4 b0 = *(const u32x4*)(&X2[s * 32 + ((g4 ^ e7) << 2)]); \
    u32x4 b1 = *(const u32x4*)(&X2[s * 32 + (((4 + g4) ^ e7) << 2)]); \
    f32x4 acc = bias1; \
    acc = __builtin_amdgcn_mfma_f32_16x16x32_f16(A10, __builtin_bit_cast(f16x8, b0), acc, 0, 0, 0); \
    acc = __builtin_amdgcn_mfma_f32_16x16x32_f16(A11, __builtin_bit_cast(f16x8, b1), acc, 0, 0, 0); \
    const int hr = 32 * mr + 16 * sb + l15; \
    u32x2 hp; \
    hp[0] = packh2(fmaxf(acc[0], 0.f), fmaxf(acc[1], 0.f)); \
    hp[1] = packh2(fmaxf(acc[2], 0.f), fmaxf(acc[3], 0.f)); \
    *(u32x2*)(&(HB)[hr * 32 + cswz]) = hp; } }

#define MM2C(C, HB) { _Pragma("unroll") for (int sb = 0; sb < 2; sb++) { \
    const int s = 128 * (C) + 32 * mr + 16 * sb + l15; \
    const int hr = 32 * mr + 16 * sb + l15; \
    u32x4 h0 = *(const u32x4*)(&(HB)[hr * 32 + ((g4 ^ e7) << 2)]); \
    u32x4 h1 = *(const u32x4*)(&(HB)[hr * 32 + (((4 + g4) ^ e7) << 2)]); \
    u32x2 ry = *(const u32x2*)(&X2[s * 32 + cswz]); \
    float2 r0 = unpackh2(ry[0]), r1 = unpackh2(ry[1]); \
    f32x4 acc = bias2; \
    acc[0] += r0.x; acc[1] += r0.y; acc[2] += r1.x; acc[3] += r1.y; \
    acc = __builtin_amdgcn_mfma_f32_16x16x32_f16(A20, __builtin_bit_cast(f16x8, h0), acc, 0, 0, 0); \
    acc = __builtin_amdgcn_mfma_f32_16x16x32_f16(A21, __builtin_bit_cast(f16x8, h1), acc, 0, 0, 0); \
    u32x2 tw; \
    tw[0] = packh2(acc[0], acc[1]); \
    tw[1] = packh2(acc[2], acc[3]); \
    *(u32x2*)(&X2[s * 32 + cswz]) = tw; } }

    MM1C(0, Hb)
    __syncthreads();
    #pragma unroll 1
    for (int c = 1; c < 8; c++) {
      uint32_t* cur = Hb + ((c & 1) << 12);
      uint32_t* prv = Hb + (((c - 1) & 1) << 12);
      MM1C(c, cur)
      __builtin_amdgcn_sched_barrier(0);
      MM2C(c - 1, prv)
      __syncthreads();
    }
    MM2C(7, Hb + 4096)
    __syncthreads();
#undef MM1C
#undef MM2C

    // ------- LN2 (thread-per-row), single pass; pads re-zeroed -------
    if (valid) {
      const int r7 = t & 7;
      u32x4 wq0 = *(const u32x4*)(&X2[t * 32 + ((0 ^ r7) << 2)]);
      u32x4 wq1 = *(const u32x4*)(&X2[t * 32 + ((1 ^ r7) << 2)]);
      u32x4 wq2 = *(const u32x4*)(&X2[t * 32 + ((2 ^ r7) << 2)]);
      u32x4 wq3 = *(const u32x4*)(&X2[t * 32 + ((3 ^ r7) << 2)]);
      u32x4 wq4 = *(const u32x4*)(&X2[t * 32 + ((4 ^ r7) << 2)]);
      u32x4 wq5 = *(const u32x4*)(&X2[t * 32 + ((5 ^ r7) << 2)]);
      u32x4 wq6 = *(const u32x4*)(&X2[t * 32 + ((6 ^ r7) << 2)]);
      u32x4 wq7 = *(const u32x4*)(&X2[t * 32 + ((7 ^ r7) << 2)]);
      float m0 = 0.f, q0 = 0.f;
#define LN2S(WQ) { _Pragma("unroll") for (int j = 0; j < 4; j++) { \
      float2 tv = unpackh2(WQ[j]); \
      m0 += tv.x + tv.y; q0 = fmaf(tv.x, tv.x, q0); q0 = fmaf(tv.y, tv.y, q0); } }
      LN2S(wq0) LN2S(wq1) LN2S(wq2) LN2S(wq3)
      LN2S(wq4) LN2S(wq5) LN2S(wq6) LN2S(wq7)
#undef LN2S
      float mu2 = m0 * (1.0f / 64.0f);
      float var2 = q0 * (1.0f / 64.0f) - mu2 * mu2;
      float rs2 = rsqrtf(var2 + 1e-5f);
#define LN2N(WQ, Q) { u32x4 o; _Pragma("unroll") for (int j = 0; j < 4; j++) { \
      float2 tv = unpackh2(WQ[j]); int d = ((Q) * 4 + j) * 2; \
      o[j] = packh2(fmaf((tv.x - mu2) * rs2, n2gl[d], n2bl[d]), \
                    fmaf((tv.y - mu2) * rs2, n2gl[d + 1], n2bl[d + 1])); } \
      *(u32x4*)(&X2[t * 32 + (((Q) ^ r7) << 2)]) = o; }
      LN2N(wq0, 0) LN2N(wq1, 1) LN2N(wq2, 2) LN2N(wq3, 3)
      LN2N(wq4, 4) LN2N(wq5, 5) LN2N(wq6, 6) LN2N(wq7, 7)
#undef LN2N
    } else {
      #pragma unroll
      for (int c = 0; c < 32; c += 4)
        *(u32x4*)(&X2[t * 32 + c]) = (u32x4){0u, 0u, 0u, 0u};  // re-zero pads
    }
    __syncthreads();                       // layer complete
  }

  // ---------------- output projection [B,S,2] ----------------
  if (valid) {
    const int r7 = t & 7;
    float a0 = out_b[0], a1 = out_b[1];
    #pragma unroll
    for (int q = 0; q < 8; q++) {
      u32x4 w = *(const u32x4*)(&X2[t * 32 + ((q ^ r7) << 2)]);
      #pragma unroll
      for (int j = 0; j < 4; j++) {
        float2 xv = unpackh2(w[j]);
        int d = (q * 4 + j) * 2;
        a0 += xv.x * out_w[d] + xv.y * out_w[d + 1];
        a1 += xv.x * out_w[64 + d] + xv.y * out_w[64 + d + 1];
      }
    }
    *(float2*)(out + (size_t)(b * 1000 + t) * 2) = make_float2(a0, a1);
  }
}

extern "C" void kernel_launch(void* const* d_in, const int* in_sizes, int n_in,
                              void* d_out, int out_size, void* d_ws, size_t ws_size,
                              hipStream_t stream) {
  const int* tokens = (const int*)d_in[0];
  const float* emb = (const float*)d_in[1];
  const float* lin_w = (const float*)d_in[2];
  const float* lin_b = (const float*)d_in[3];
  const float* ff1_w = (const float*)d_in[4];
  const float* ff1_b = (const float*)d_in[5];
  const float* ff2_w = (const float*)d_in[6];
  const float* ff2_b = (const float*)d_in[7];
  const float* n1_g = (const float*)d_in[8];
  const float* n1_b = (const float*)d_in[9];
  const float* n2_g = (const float*)d_in[10];
  const float* n2_b = (const float*)d_in[11];
  const float* out_w = (const float*)d_in[12];
  const float* out_b = (const float*)d_in[13];
  float* out = (float*)d_out;

  f16* w1h = (f16*)d_ws;                         // 32 KiB
  f16* w2h = w1h + 16384;                        // 32 KiB
  float* petab = (float*)((char*)d_ws + 65536);  // 250 KiB (1000*64 f32)
  const size_t need = 65536 + 64000 * 4;
  const bool use_pe = (ws_size >= need);
  float* pe_arg = use_pe ? petab : nullptr;

  int pack_threads = 32768 + (use_pe ? 64000 : 0);
  int pack_blocks = (pack_threads + 255) / 256;
  pack_weights_kernel<<<pack_blocks, 256, 0, stream>>>(ff1_w, ff2_w, w1h, w2h, pe_arg);
  aat_kernel<<<512, TPB, 0, stream>>>(tokens, emb, lin_w, lin_b, ff1_b, ff2_b,
                                      n1_g, n1_b, n2_g, n2_b, out_w, out_b,
                                      w1h, w2h, pe_arg, out);
}

// Round 17
// 280.862 us; speedup vs baseline: 1.3304x; 1.1004x over previous
//
#include <hip/hip_runtime.h>
#include <stdint.h>

#define TPB 1024
#define NL 4

typedef _Float16 f16;
typedef _Float16 half2v __attribute__((ext_vector_type(2)));
typedef _Float16 f16x8 __attribute__((ext_vector_type(8)));
typedef float f32x4 __attribute__((ext_vector_type(4)));
typedef uint32_t u32x2 __attribute__((ext_vector_type(2)));
typedef uint32_t u32x4 __attribute__((ext_vector_type(4)));

// X2/Hb u32 index for row r, u32-col c: 16B-block XOR swizzle (block ^= r&7).
#define XIU(r, c) ((r) * 32 + (((((c) >> 2) ^ ((r) & 7))) << 2) + ((c) & 3))

static __device__ __forceinline__ uint32_t packh2(float a, float b) {
  half2v h;
  h.x = (_Float16)a;
  h.y = (_Float16)b;
  return __builtin_bit_cast(uint32_t, h);
}
static __device__ __forceinline__ float2 unpackh2(uint32_t u) {
  half2v h = __builtin_bit_cast(half2v, u);
  return make_float2((float)h.x, (float)h.y);
}

__global__ void pack_weights_kernel(const float* __restrict__ ff1_w,
                                    const float* __restrict__ ff2_w,
                                    f16* __restrict__ w1h,
                                    f16* __restrict__ w2h,
                                    float* __restrict__ petab) {
  int idx = blockIdx.x * blockDim.x + threadIdx.x;
  if (idx < 16384) {
    w1h[idx] = (f16)ff1_w[idx];
  } else if (idx < 32768) {
    w2h[idx - 16384] = (f16)ff2_w[idx - 16384];
  } else if (petab != nullptr && idx < 32768 + 64000) {
    int j = idx - 32768;
    int s = j >> 6, d = j & 63;
    float div = exp2f(-0.4152410118609203f * (float)(d >> 1));
    float ang = (float)s * div;
    petab[j] = (d & 1) ? cosf(ang) : sinf(ang);
  }
}

// R17 = R16's software-pipelined FF (8 chunks x 128 rows, dual 16KB H bufs,
// mm1(c) || mm2(c-1) per phase -- within the 64-VGPR budget) + R13's
// STREAMING two-pass LN. R16's single-pass LN held 8 x u32x4 (32 regs) of
// row state across the stats->normalize span and spilled (WRITE 4->72 MB,
// the 128 B/thread signature). Rule from R9/R11/R15/R16: any phase holding
// >=32 u32 of row state spills at the backend's hard 64-VGPR choice; the
// streaming LN (4 live regs, two LDS passes) is the only form that fits.
__global__ __launch_bounds__(TPB) void aat_kernel(
    const int* __restrict__ tokens, const float* __restrict__ emb,
    const float* __restrict__ lin_w, const float* __restrict__ lin_b,
    const float* __restrict__ ff1_b, const float* __restrict__ ff2_b,
    const float* __restrict__ n1_g, const float* __restrict__ n1_b,
    const float* __restrict__ n2_g, const float* __restrict__ n2_b,
    const float* __restrict__ out_w, const float* __restrict__ out_b,
    const f16* __restrict__ w1h, const f16* __restrict__ w2h,
    const float* __restrict__ petab, float* __restrict__ out) {
  __shared__ __align__(16) uint32_t X2[1024 * 32];  // 131072 B
  __shared__ __align__(16) uint32_t Hb[2 * 4096];   // 32768 B: 2 H bufs / redbuf

  const int t = threadIdx.x;
  const int b = blockIdx.x;
  const int lane = t & 63;
  const int wv = t >> 6;                  // 0..15
  const bool valid = (t < 1000);
  float* redbuf = (float*)Hb;             // [32][64] f32 (avg phase)
  float* avgbuf = (float*)(Hb + 2048);    // 64 f32
  float* attnbuf = (float*)(Hb + 2112);   // 64 f32, 8B-aligned

  // ---------------- embed * sqrt(d) + positional encoding -> X2 ----------------
  if (valid) {
    int tok = tokens[b * 1000 + t];
    const float4* ev = (const float4*)(emb + (size_t)tok * 64);
    const int r7 = t & 7;
    if (petab != nullptr) {
      const float4* pv = (const float4*)(petab + (size_t)t * 64);
      #pragma unroll
      for (int q = 0; q < 8; q++) {
        float4 v0 = ev[2 * q], v1 = ev[2 * q + 1];
        float4 p0 = pv[2 * q], p1 = pv[2 * q + 1];
        u32x4 w;
        w[0] = packh2(fmaf(v0.x, 8.f, p0.x), fmaf(v0.y, 8.f, p0.y));
        w[1] = packh2(fmaf(v0.z, 8.f, p0.z), fmaf(v0.w, 8.f, p0.w));
        w[2] = packh2(fmaf(v1.x, 8.f, p1.x), fmaf(v1.y, 8.f, p1.y));
        w[3] = packh2(fmaf(v1.z, 8.f, p1.z), fmaf(v1.w, 8.f, p1.w));
        *(u32x4*)(&X2[t * 32 + ((q ^ r7) << 2)]) = w;
      }
    } else {
      float fs = (float)t;
      #pragma unroll
      for (int q = 0; q < 8; q++) {
        float4 v0 = ev[2 * q], v1 = ev[2 * q + 1];
        float d0 = exp2f(-0.4152410118609203f * (float)(4 * q));
        float d1 = exp2f(-0.4152410118609203f * (float)(4 * q + 1));
        float d2 = exp2f(-0.4152410118609203f * (float)(4 * q + 2));
        float d3 = exp2f(-0.4152410118609203f * (float)(4 * q + 3));
        u32x4 w;
        w[0] = packh2(fmaf(v0.x, 8.f, sinf(fs * d0)), fmaf(v0.y, 8.f, cosf(fs * d0)));
        w[1] = packh2(fmaf(v0.z, 8.f, sinf(fs * d1)), fmaf(v0.w, 8.f, cosf(fs * d1)));
        w[2] = packh2(fmaf(v1.x, 8.f, sinf(fs * d2)), fmaf(v1.y, 8.f, cosf(fs * d2)));
        w[3] = packh2(fmaf(v1.z, 8.f, sinf(fs * d3)), fmaf(v1.w, 8.f, cosf(fs * d3)));
        *(u32x4*)(&X2[t * 32 + ((q ^ r7) << 2)]) = w;
      }
    }
  } else {
    #pragma unroll
    for (int c = 0; c < 32; c += 4)
      *(u32x4*)(&X2[t * 32 + c]) = (u32x4){0u, 0u, 0u, 0u};  // pad rows zero
  }
  __syncthreads();

  const int l15 = lane & 15;
  const int g4 = lane >> 4;               // 0..3
  const int e7 = l15 & 7;                 // (row)&7 for all FF rows of this lane
  const int nt = wv & 3;                  // output-tile (16 cols of W1/W2)
  const int mr = wv >> 2;                 // row-group within a 128-row chunk
  const int cw = 8 * nt + 2 * g4;         // u32-col base of this lane's 4 outputs
  const int cswz = (((cw >> 2) ^ e7) << 2) + (cw & 3);  // swizzled col offset

  #pragma unroll 1
  for (int l = 0; l < NL; l++) {
    const float* n1g = n1_g + l * 64;
    const float* n1b = n1_b + l * 64;
    const float* n2gl = n2_g + l * 64;
    const float* n2bl = n2_b + l * 64;

    // Per-wave weight tile (LICM hoists to layer scope: 24 VGPRs, fits)
    const f16* w1p = w1h + l * 4096 + (16 * nt + l15) * 64 + 8 * g4;
    f16x8 A10 = *(const f16x8*)(w1p);
    f16x8 A11 = *(const f16x8*)(w1p + 32);
    const f16* w2p = w2h + l * 4096 + (16 * nt + l15) * 64 + 8 * g4;
    f16x8 A20 = *(const f16x8*)(w2p);
    f16x8 A21 = *(const f16x8*)(w2p + 32);
    f32x4 bias1 = *(const f32x4*)(ff1_b + l * 64 + 16 * nt + 4 * g4);
    f32x4 bias2 = *(const f32x4*)(ff2_b + l * 64 + 16 * nt + 4 * g4);

    // ------- avg over sequence: column-parallel partials into redbuf -------
    {
      int cp = t & 31, rg = t >> 5;
      float s0 = 0.f, s1 = 0.f;
      for (int r = rg; r < 1000; r += 32) {
        float2 v = unpackh2(X2[XIU(r, cp)]);
        s0 += v.x;
        s1 += v.y;
      }
      redbuf[rg * 64 + 2 * cp] = s0;
      redbuf[rg * 64 + 2 * cp + 1] = s1;
    }
    __syncthreads();                       // bar 1
    if (t < 64) {
      float ssum = 0.f;
      #pragma unroll
      for (int w = 0; w < 32; w++) ssum += redbuf[w * 64 + t];
      avgbuf[t] = ssum * 1e-3f;
    }
    if (t < 64) {  // attn[o] = lin_b[o] + sum_d avg[d]*lin_w[o][d]
      const float* wr = lin_w + (size_t)(l * 64 + t) * 64;
      float a0 = lin_b[l * 64 + t], a1 = 0.f, a2 = 0.f, a3 = 0.f;
      #pragma unroll
      for (int d = 0; d < 64; d += 4) {
        a0 += avgbuf[d] * wr[d];
        a1 += avgbuf[d + 1] * wr[d + 1];
        a2 += avgbuf[d + 2] * wr[d + 2];
        a3 += avgbuf[d + 3] * wr[d + 3];
      }
      attnbuf[t] = (a0 + a1) + (a2 + a3);
    }
    __syncthreads();                       // bar 2

    // ------- LN1 (thread t = row t), streaming two-pass (spill-free) -------
    if (valid) {
      const float2* at2 = (const float2*)attnbuf;
      const int r7 = t & 7;
      float m0 = 0.f, q0 = 0.f;
      #pragma unroll
      for (int q = 0; q < 8; q++) {
        u32x4 w = *(const u32x4*)(&X2[t * 32 + ((q ^ r7) << 2)]);
        #pragma unroll
        for (int j = 0; j < 4; j++) {
          float2 xv = unpackh2(w[j]);
          float2 at = at2[q * 4 + j];
          float a0 = xv.x + at.x, a1 = xv.y + at.y;
          m0 += a0 + a1;
          q0 = fmaf(a0, a0, q0);
          q0 = fmaf(a1, a1, q0);
        }
      }
      float mu = m0 * (1.0f / 64.0f);
      float var = q0 * (1.0f / 64.0f) - mu * mu;
      float rs = rsqrtf(var + 1e-5f);
      #pragma unroll
      for (int q = 0; q < 8; q++) {
        u32x4 w = *(const u32x4*)(&X2[t * 32 + ((q ^ r7) << 2)]);
        u32x4 o;
        #pragma unroll
        for (int j = 0; j < 4; j++) {
          float2 xv = unpackh2(w[j]);
          float2 at = at2[q * 4 + j];
          int d = (q * 4 + j) * 2;
          float a0 = xv.x + at.x, a1 = xv.y + at.y;
          o[j] = packh2(fmaf((a0 - mu) * rs, n1g[d], n1b[d]),
                        fmaf((a1 - mu) * rs, n1g[d + 1], n1b[d + 1]));
        }
        *(u32x4*)(&X2[t * 32 + ((q ^ r7) << 2)]) = o;
      }
    }
    __syncthreads();                       // bar 3: Y visible to FF waves

    // ------- FF: 8 chunks of 128 rows, software-pipelined (dual H bufs) -------
#define MM1C(C, HB) { _Pragma("unroll") for (int sb = 0; sb < 2; sb++) { \
    const int s = 128 * (C) + 32 * mr + 16 * sb + l15; \
    u32x4 b0 = *(const u32x4*)(&X2[s * 32 + ((g4 ^ e7) << 2)]); \
    u32x4 b1 = *(const u32x4*)(&X2[s * 32 + (((4 + g4) ^ e7) << 2)]); \
    f32x4 acc = bias1; \
    acc = __builtin_amdgcn_mfma_f32_16x16x32_f16(A10, __builtin_bit_cast(f16x8, b0), acc, 0, 0, 0); \
    acc = __builtin_amdgcn_mfma_f32_16x16x32_f16(A11, __builtin_bit_cast(f16x8, b1), acc, 0, 0, 0); \
    const int hr = 32 * mr + 16 * sb + l15; \
    u32x2 hp; \
    hp[0] = packh2(fmaxf(acc[0], 0.f), fmaxf(acc[1], 0.f)); \
    hp[1] = packh2(fmaxf(acc[2], 0.f), fmaxf(acc[3], 0.f)); \
    *(u32x2*)(&(HB)[hr * 32 + cswz]) = hp; } }

#define MM2C(C, HB) { _Pragma("unroll") for (int sb = 0; sb < 2; sb++) { \
    const int s = 128 * (C) + 32 * mr + 16 * sb + l15; \
    const int hr = 32 * mr + 16 * sb + l15; \
    u32x4 h0 = *(const u32x4*)(&(HB)[hr * 32 + ((g4 ^ e7) << 2)]); \
    u32x4 h1 = *(const u32x4*)(&(HB)[hr * 32 + (((4 + g4) ^ e7) << 2)]); \
    u32x2 ry = *(const u32x2*)(&X2[s * 32 + cswz]); \
    float2 r0 = unpackh2(ry[0]), r1 = unpackh2(ry[1]); \
    f32x4 acc = bias2; \
    acc[0] += r0.x; acc[1] += r0.y; acc[2] += r1.x; acc[3] += r1.y; \
    acc = __builtin_amdgcn_mfma_f32_16x16x32_f16(A20, __builtin_bit_cast(f16x8, h0), acc, 0, 0, 0); \
    acc = __builtin_amdgcn_mfma_f32_16x16x32_f16(A21, __builtin_bit_cast(f16x8, h1), acc, 0, 0, 0); \
    u32x2 tw; \
    tw[0] = packh2(acc[0], acc[1]); \
    tw[1] = packh2(acc[2], acc[3]); \
    *(u32x2*)(&X2[s * 32 + cswz]) = tw; } }

    MM1C(0, Hb)
    __syncthreads();
    #pragma unroll 1
    for (int c = 1; c < 8; c++) {
      uint32_t* cur = Hb + ((c & 1) << 12);
      uint32_t* prv = Hb + (((c - 1) & 1) << 12);
      MM1C(c, cur)
      __builtin_amdgcn_sched_barrier(0);
      MM2C(c - 1, prv)
      __syncthreads();
    }
    MM2C(7, Hb + 4096)
    __syncthreads();
#undef MM1C
#undef MM2C

    // ------- LN2 (thread-per-row), streaming two-pass; pads re-zeroed -------
    if (valid) {
      const int r7 = t & 7;
      float m0 = 0.f, q0 = 0.f;
      #pragma unroll
      for (int q = 0; q < 8; q++) {
        u32x4 w = *(const u32x4*)(&X2[t * 32 + ((q ^ r7) << 2)]);
        #pragma unroll
        for (int j = 0; j < 4; j++) {
          float2 tv = unpackh2(w[j]);
          m0 += tv.x + tv.y;
          q0 = fmaf(tv.x, tv.x, q0);
          q0 = fmaf(tv.y, tv.y, q0);
        }
      }
      float mu2 = m0 * (1.0f / 64.0f);
      float var2 = q0 * (1.0f / 64.0f) - mu2 * mu2;
      float rs2 = rsqrtf(var2 + 1e-5f);
      #pragma unroll
      for (int q = 0; q < 8; q++) {
        u32x4 w = *(const u32x4*)(&X2[t * 32 + ((q ^ r7) << 2)]);
        u32x4 o;
        #pragma unroll
        for (int j = 0; j < 4; j++) {
          float2 tv = unpackh2(w[j]);
          int d = (q * 4 + j) * 2;
          o[j] = packh2(fmaf((tv.x - mu2) * rs2, n2gl[d], n2bl[d]),
                        fmaf((tv.y - mu2) * rs2, n2gl[d + 1], n2bl[d + 1]));
        }
        *(u32x4*)(&X2[t * 32 + ((q ^ r7) << 2)]) = o;
      }
    } else {
      #pragma unroll
      for (int c = 0; c < 32; c += 4)
        *(u32x4*)(&X2[t * 32 + c]) = (u32x4){0u, 0u, 0u, 0u};  // re-zero pads
    }
    __syncthreads();                       // layer complete
  }

  // ---------------- output projection [B,S,2] ----------------
  if (valid) {
    const int r7 = t & 7;
    float a0 = out_b[0], a1 = out_b[1];
    #pragma unroll
    for (int q = 0; q < 8; q++) {
      u32x4 w = *(const u32x4*)(&X2[t * 32 + ((q ^ r7) << 2)]);
      #pragma unroll
      for (int j = 0; j < 4; j++) {
        float2 xv = unpackh2(w[j]);
        int d = (q * 4 + j) * 2;
        a0 += xv.x * out_w[d] + xv.y * out_w[d + 1];
        a1 += xv.x * out_w[64 + d] + xv.y * out_w[64 + d + 1];
      }
    }
    *(float2*)(out + (size_t)(b * 1000 + t) * 2) = make_float2(a0, a1);
  }
}

extern "C" void kernel_launch(void* const* d_in, const int* in_sizes, int n_in,
                              void* d_out, int out_size, void* d_ws, size_t ws_size,
                              hipStream_t stream) {
  const int* tokens = (const int*)d_in[0];
  const float* emb = (const float*)d_in[1];
  const float* lin_w = (const float*)d_in[2];
  const float* lin_b = (const float*)d_in[3];
  const float* ff1_w = (const float*)d_in[4];
  const float* ff1_b = (const float*)d_in[5];
  const float* ff2_w = (const float*)d_in[6];
  const float* ff2_b = (const float*)d_in[7];
  const float* n1_g = (const float*)d_in[8];
  const float* n1_b = (const float*)d_in[9];
  const float* n2_g = (const float*)d_in[10];
  const float* n2_b = (const float*)d_in[11];
  const float* out_w = (const float*)d_in[12];
  const float* out_b = (const float*)d_in[13];
  float* out = (float*)d_out;

  f16* w1h = (f16*)d_ws;                         // 32 KiB
  f16* w2h = w1h + 16384;                        // 32 KiB
  float* petab = (float*)((char*)d_ws + 65536);  // 250 KiB (1000*64 f32)
  const size_t need = 65536 + 64000 * 4;
  const bool use_pe = (ws_size >= need);
  float* pe_arg = use_pe ? petab : nullptr;

  int pack_threads = 32768 + (use_pe ? 64000 : 0);
  int pack_blocks = (pack_threads + 255) / 256;
  pack_weights_kernel<<<pack_blocks, 256, 0, stream>>>(ff1_w, ff2_w, w1h, w2h, pe_arg);
  aat_kernel<<<512, TPB, 0, stream>>>(tokens, emb, lin_w, lin_b, ff1_b, ff2_b,
                                      n1_g, n1_b, n2_g, n2_b, out_w, out_b,
                                      w1h, w2h, pe_arg, out);
}

// Round 18
// 269.506 us; speedup vs baseline: 1.3865x; 1.0421x over previous
//
#include <hip/hip_runtime.h>
#include <stdint.h>

#define TPB 1024
#define NL 4

typedef _Float16 f16;
typedef _Float16 half2v __attribute__((ext_vector_type(2)));
typedef _Float16 f16x8 __attribute__((ext_vector_type(8)));
typedef float f32x4 __attribute__((ext_vector_type(4)));
typedef uint32_t u32x2 __attribute__((ext_vector_type(2)));
typedef uint32_t u32x4 __attribute__((ext_vector_type(4)));

// X2/Hb u32 index for row r, u32-col c: 16B-block XOR swizzle (block ^= r&7).
#define XIU(r, c) ((r) * 32 + (((((c) >> 2) ^ ((r) & 7))) << 2) + ((c) & 3))

static __device__ __forceinline__ uint32_t packh2(float a, float b) {
  half2v h;
  h.x = (_Float16)a;
  h.y = (_Float16)b;
  return __builtin_bit_cast(uint32_t, h);
}
static __device__ __forceinline__ float2 unpackh2(uint32_t u) {
  half2v h = __builtin_bit_cast(half2v, u);
  return make_float2((float)h.x, (float)h.y);
}
static __device__ __forceinline__ float fdot2h(uint32_t a, uint32_t b, float c) {
#if __has_builtin(__builtin_amdgcn_fdot2)
  return __builtin_amdgcn_fdot2(__builtin_bit_cast(half2v, a),
                                __builtin_bit_cast(half2v, b), c, false);
#else
  half2v x = __builtin_bit_cast(half2v, a);
  half2v y = __builtin_bit_cast(half2v, b);
  return c + (float)x.x * (float)y.x + (float)x.y * (float)y.y;
#endif
}

__global__ void pack_weights_kernel(const float* __restrict__ ff1_w,
                                    const float* __restrict__ ff2_w,
                                    f16* __restrict__ w1h,
                                    f16* __restrict__ w2h,
                                    float* __restrict__ petab) {
  int idx = blockIdx.x * blockDim.x + threadIdx.x;
  if (idx < 16384) {
    w1h[idx] = (f16)ff1_w[idx];
  } else if (idx < 32768) {
    w2h[idx - 16384] = (f16)ff2_w[idx - 16384];
  } else if (petab != nullptr && idx < 32768 + 64000) {
    int j = idx - 32768;
    int s = j >> 6, d = j & 63;
    float div = exp2f(-0.4152410118609203f * (float)(d >> 1));
    float ang = (float)s * div;
    petab[j] = (d & 1) ? cosf(ang) : sinf(ang);
  }
}

// R18 = R17 (214us, spill-free at the hard 64-VGPR ceiling) + fdot2-based LN
// stats. R17's PMC: VALU 48.6% busy with cvt-chain-heavy LN stats (8 ops per
// f16 pair). v_dot2_f32_f16 does a.x*b.x+a.y*b.y+c in ONE op on packed f16:
//  - LN1: Sa = Sx + S_A, Sa2 = Sx2 + 2*S(x.attn) + Q_A, with S_A/Q_A
//    row-independent scalars (wave0 butterfly, once/layer); row sums = 96
//    fdot2 (vs ~256 ops). attn packed to f16 for the cross term only
//    (error ~5e-5 << f16 output ulp); normalize keeps f32 attn.
//  - LN2: fdot2(t,ones)+fdot2(t,t), exact.
// ~350 VALU ops/thread/layer saved; peak liveness DECREASES (fewer temps).
__global__ __launch_bounds__(TPB) void aat_kernel(
    const int* __restrict__ tokens, const float* __restrict__ emb,
    const float* __restrict__ lin_w, const float* __restrict__ lin_b,
    const float* __restrict__ ff1_b, const float* __restrict__ ff2_b,
    const float* __restrict__ n1_g, const float* __restrict__ n1_b,
    const float* __restrict__ n2_g, const float* __restrict__ n2_b,
    const float* __restrict__ out_w, const float* __restrict__ out_b,
    const f16* __restrict__ w1h, const f16* __restrict__ w2h,
    const float* __restrict__ petab, float* __restrict__ out) {
  __shared__ __align__(16) uint32_t X2[1024 * 32];  // 131072 B
  __shared__ __align__(16) uint32_t Hb[2 * 4096];   // 32768 B: 2 H bufs / redbuf

  const int t = threadIdx.x;
  const int b = blockIdx.x;
  const int lane = t & 63;
  const int wv = t >> 6;                  // 0..15
  const bool valid = (t < 1000);
  float* redbuf = (float*)Hb;             // [32][64] f32 (avg phase)
  float* avgbuf = (float*)(Hb + 2048);    // 64 f32
  float* attnbuf = (float*)(Hb + 2112);   // 64 f32, 8B-aligned
  uint32_t* attnpk = Hb + 2176;           // 32 u32: attn as f16 pairs (16B-aligned)
  float* saqa = (float*)(Hb + 2208);      // S_A, Q_A scalars
  // (all of the above die before FF writes Hb's buffers)

  // ---------------- embed * sqrt(d) + positional encoding -> X2 ----------------
  if (valid) {
    int tok = tokens[b * 1000 + t];
    const float4* ev = (const float4*)(emb + (size_t)tok * 64);
    const int r7 = t & 7;
    if (petab != nullptr) {
      const float4* pv = (const float4*)(petab + (size_t)t * 64);
      #pragma unroll
      for (int q = 0; q < 8; q++) {
        float4 v0 = ev[2 * q], v1 = ev[2 * q + 1];
        float4 p0 = pv[2 * q], p1 = pv[2 * q + 1];
        u32x4 w;
        w[0] = packh2(fmaf(v0.x, 8.f, p0.x), fmaf(v0.y, 8.f, p0.y));
        w[1] = packh2(fmaf(v0.z, 8.f, p0.z), fmaf(v0.w, 8.f, p0.w));
        w[2] = packh2(fmaf(v1.x, 8.f, p1.x), fmaf(v1.y, 8.f, p1.y));
        w[3] = packh2(fmaf(v1.z, 8.f, p1.z), fmaf(v1.w, 8.f, p1.w));
        *(u32x4*)(&X2[t * 32 + ((q ^ r7) << 2)]) = w;
      }
    } else {
      float fs = (float)t;
      #pragma unroll
      for (int q = 0; q < 8; q++) {
        float4 v0 = ev[2 * q], v1 = ev[2 * q + 1];
        float d0 = exp2f(-0.4152410118609203f * (float)(4 * q));
        float d1 = exp2f(-0.4152410118609203f * (float)(4 * q + 1));
        float d2 = exp2f(-0.4152410118609203f * (float)(4 * q + 2));
        float d3 = exp2f(-0.4152410118609203f * (float)(4 * q + 3));
        u32x4 w;
        w[0] = packh2(fmaf(v0.x, 8.f, sinf(fs * d0)), fmaf(v0.y, 8.f, cosf(fs * d0)));
        w[1] = packh2(fmaf(v0.z, 8.f, sinf(fs * d1)), fmaf(v0.w, 8.f, cosf(fs * d1)));
        w[2] = packh2(fmaf(v1.x, 8.f, sinf(fs * d2)), fmaf(v1.y, 8.f, cosf(fs * d2)));
        w[3] = packh2(fmaf(v1.z, 8.f, sinf(fs * d3)), fmaf(v1.w, 8.f, cosf(fs * d3)));
        *(u32x4*)(&X2[t * 32 + ((q ^ r7) << 2)]) = w;
      }
    }
  } else {
    #pragma unroll
    for (int c = 0; c < 32; c += 4)
      *(u32x4*)(&X2[t * 32 + c]) = (u32x4){0u, 0u, 0u, 0u};  // pad rows zero
  }
  __syncthreads();

  const int l15 = lane & 15;
  const int g4 = lane >> 4;               // 0..3
  const int e7 = l15 & 7;                 // (row)&7 for all FF rows of this lane
  const int nt = wv & 3;                  // output-tile (16 cols of W1/W2)
  const int mr = wv >> 2;                 // row-group within a 128-row chunk
  const int cw = 8 * nt + 2 * g4;         // u32-col base of this lane's 4 outputs
  const int cswz = (((cw >> 2) ^ e7) << 2) + (cw & 3);  // swizzled col offset
  const uint32_t ONESPK = 0x3C003C00u;    // f16 pair (1.0, 1.0)

  #pragma unroll 1
  for (int l = 0; l < NL; l++) {
    const float* n1g = n1_g + l * 64;
    const float* n1b = n1_b + l * 64;
    const float* n2gl = n2_g + l * 64;
    const float* n2bl = n2_b + l * 64;

    // Per-wave weight tile (LICM hoists to layer scope: 24 VGPRs, fits)
    const f16* w1p = w1h + l * 4096 + (16 * nt + l15) * 64 + 8 * g4;
    f16x8 A10 = *(const f16x8*)(w1p);
    f16x8 A11 = *(const f16x8*)(w1p + 32);
    const f16* w2p = w2h + l * 4096 + (16 * nt + l15) * 64 + 8 * g4;
    f16x8 A20 = *(const f16x8*)(w2p);
    f16x8 A21 = *(const f16x8*)(w2p + 32);
    f32x4 bias1 = *(const f32x4*)(ff1_b + l * 64 + 16 * nt + 4 * g4);
    f32x4 bias2 = *(const f32x4*)(ff2_b + l * 64 + 16 * nt + 4 * g4);

    // ------- avg over sequence: column-parallel partials into redbuf -------
    {
      int cp = t & 31, rg = t >> 5;
      float s0 = 0.f, s1 = 0.f;
      for (int r = rg; r < 1000; r += 32) {
        float2 v = unpackh2(X2[XIU(r, cp)]);
        s0 += v.x;
        s1 += v.y;
      }
      redbuf[rg * 64 + 2 * cp] = s0;
      redbuf[rg * 64 + 2 * cp + 1] = s1;
    }
    __syncthreads();                       // bar 1
    if (t < 64) {
      float ssum = 0.f;
      #pragma unroll
      for (int w = 0; w < 32; w++) ssum += redbuf[w * 64 + t];
      avgbuf[t] = ssum * 1e-3f;
    }
    if (t < 64) {  // attn[o] = lin_b[o] + sum_d avg[d]*lin_w[o][d]
      const float* wr = lin_w + (size_t)(l * 64 + t) * 64;
      float a0 = lin_b[l * 64 + t], a1 = 0.f, a2 = 0.f, a3 = 0.f;
      #pragma unroll
      for (int d = 0; d < 64; d += 4) {
        a0 += avgbuf[d] * wr[d];
        a1 += avgbuf[d + 1] * wr[d + 1];
        a2 += avgbuf[d + 2] * wr[d + 2];
        a3 += avgbuf[d + 3] * wr[d + 3];
      }
      float av = (a0 + a1) + (a2 + a3);
      attnbuf[t] = av;
      // packed f16 attn pairs (for LN1 cross-term fdot2)
      float pr = __shfl_xor(av, 1, 64);
      if ((t & 1) == 0) attnpk[t >> 1] = packh2(av, pr);
      // S_A = sum(attn), Q_A = sum(attn^2): wave0 butterfly
      float sa = av, qa = av * av;
      #pragma unroll
      for (int m = 1; m < 64; m <<= 1) {
        sa += __shfl_xor(sa, m, 64);
        qa += __shfl_xor(qa, m, 64);
      }
      if (t == 0) {
        saqa[0] = sa;
        saqa[1] = qa;
      }
    }
    __syncthreads();                       // bar 2

    // ------- LN1 (thread t = row t): fdot2 stats + streaming normalize -------
    if (valid) {
      const float2* at2 = (const float2*)attnbuf;
      const int r7 = t & 7;
      float sx = 0.f, sxx = 0.f, sxa = 0.f;
      #pragma unroll
      for (int q = 0; q < 8; q++) {
        u32x4 w = *(const u32x4*)(&X2[t * 32 + ((q ^ r7) << 2)]);
        u32x4 ap = *(const u32x4*)(&attnpk[q * 4]);
        #pragma unroll
        for (int j = 0; j < 4; j++) {
          sx = fdot2h(w[j], ONESPK, sx);
          sxx = fdot2h(w[j], w[j], sxx);
          sxa = fdot2h(w[j], ap[j], sxa);
        }
      }
      float m0 = sx + saqa[0];
      float q0 = sxx + 2.f * sxa + saqa[1];
      float mu = m0 * (1.0f / 64.0f);
      float var = q0 * (1.0f / 64.0f) - mu * mu;
      float rs = rsqrtf(var + 1e-5f);
      #pragma unroll
      for (int q = 0; q < 8; q++) {
        u32x4 w = *(const u32x4*)(&X2[t * 32 + ((q ^ r7) << 2)]);
        u32x4 o;
        #pragma unroll
        for (int j = 0; j < 4; j++) {
          float2 xv = unpackh2(w[j]);
          float2 at = at2[q * 4 + j];
          int d = (q * 4 + j) * 2;
          float a0 = xv.x + at.x, a1 = xv.y + at.y;
          o[j] = packh2(fmaf((a0 - mu) * rs, n1g[d], n1b[d]),
                        fmaf((a1 - mu) * rs, n1g[d + 1], n1b[d + 1]));
        }
        *(u32x4*)(&X2[t * 32 + ((q ^ r7) << 2)]) = o;
      }
    }
    __syncthreads();                       // bar 3: Y visible to FF waves

    // ------- FF: 8 chunks of 128 rows, software-pipelined (dual H bufs) -------
#define MM1C(C, HB) { _Pragma("unroll") for (int sb = 0; sb < 2; sb++) { \
    const int s = 128 * (C) + 32 * mr + 16 * sb + l15; \
    u32x4 b0 = *(const u32x4*)(&X2[s * 32 + ((g4 ^ e7) << 2)]); \
    u32x4 b1 = *(const u32x4*)(&X2[s * 32 + (((4 + g4) ^ e7) << 2)]); \
    f32x4 acc = bias1; \
    acc = __builtin_amdgcn_mfma_f32_16x16x32_f16(A10, __builtin_bit_cast(f16x8, b0), acc, 0, 0, 0); \
    acc = __builtin_amdgcn_mfma_f32_16x16x32_f16(A11, __builtin_bit_cast(f16x8, b1), acc, 0, 0, 0); \
    const int hr = 32 * mr + 16 * sb + l15; \
    u32x2 hp; \
    hp[0] = packh2(fmaxf(acc[0], 0.f), fmaxf(acc[1], 0.f)); \
    hp[1] = packh2(fmaxf(acc[2], 0.f), fmaxf(acc[3], 0.f)); \
    *(u32x2*)(&(HB)[hr * 32 + cswz]) = hp; } }

#define MM2C(C, HB) { _Pragma("unroll") for (int sb = 0; sb < 2; sb++) { \
    const int s = 128 * (C) + 32 * mr + 16 * sb + l15; \
    const int hr = 32 * mr + 16 * sb + l15; \
    u32x4 h0 = *(const u32x4*)(&(HB)[hr * 32 + ((g4 ^ e7) << 2)]); \
    u32x4 h1 = *(const u32x4*)(&(HB)[hr * 32 + (((4 + g4) ^ e7) << 2)]); \
    u32x2 ry = *(const u32x2*)(&X2[s * 32 + cswz]); \
    float2 r0 = unpackh2(ry[0]), r1 = unpackh2(ry[1]); \
    f32x4 acc = bias2; \
    acc[0] += r0.x; acc[1] += r0.y; acc[2] += r1.x; acc[3] += r1.y; \
    acc = __builtin_amdgcn_mfma_f32_16x16x32_f16(A20, __builtin_bit_cast(f16x8, h0), acc, 0, 0, 0); \
    acc = __builtin_amdgcn_mfma_f32_16x16x32_f16(A21, __builtin_bit_cast(f16x8, h1), acc, 0, 0, 0); \
    u32x2 tw; \
    tw[0] = packh2(acc[0], acc[1]); \
    tw[1] = packh2(acc[2], acc[3]); \
    *(u32x2*)(&X2[s * 32 + cswz]) = tw; } }

    MM1C(0, Hb)
    __syncthreads();
    #pragma unroll 1
    for (int c = 1; c < 8; c++) {
      uint32_t* cur = Hb + ((c & 1) << 12);
      uint32_t* prv = Hb + (((c - 1) & 1) << 12);
      MM1C(c, cur)
      __builtin_amdgcn_sched_barrier(0);
      MM2C(c - 1, prv)
      __syncthreads();
    }
    MM2C(7, Hb + 4096)
    __syncthreads();
#undef MM1C
#undef MM2C

    // ------- LN2 (thread-per-row): fdot2 stats + streaming normalize -------
    if (valid) {
      const int r7 = t & 7;
      float m0 = 0.f, q0 = 0.f;
      #pragma unroll
      for (int q = 0; q < 8; q++) {
        u32x4 w = *(const u32x4*)(&X2[t * 32 + ((q ^ r7) << 2)]);
        #pragma unroll
        for (int j = 0; j < 4; j++) {
          m0 = fdot2h(w[j], ONESPK, m0);
          q0 = fdot2h(w[j], w[j], q0);
        }
      }
      float mu2 = m0 * (1.0f / 64.0f);
      float var2 = q0 * (1.0f / 64.0f) - mu2 * mu2;
      float rs2 = rsqrtf(var2 + 1e-5f);
      #pragma unroll
      for (int q = 0; q < 8; q++) {
        u32x4 w = *(const u32x4*)(&X2[t * 32 + ((q ^ r7) << 2)]);
        u32x4 o;
        #pragma unroll
        for (int j = 0; j < 4; j++) {
          float2 tv = unpackh2(w[j]);
          int d = (q * 4 + j) * 2;
          o[j] = packh2(fmaf((tv.x - mu2) * rs2, n2gl[d], n2bl[d]),
                        fmaf((tv.y - mu2) * rs2, n2gl[d + 1], n2bl[d + 1]));
        }
        *(u32x4*)(&X2[t * 32 + ((q ^ r7) << 2)]) = o;
      }
    } else {
      #pragma unroll
      for (int c = 0; c < 32; c += 4)
        *(u32x4*)(&X2[t * 32 + c]) = (u32x4){0u, 0u, 0u, 0u};  // re-zero pads
    }
    __syncthreads();                       // layer complete
  }

  // ---------------- output projection [B,S,2] ----------------
  if (valid) {
    const int r7 = t & 7;
    float a0 = out_b[0], a1 = out_b[1];
    #pragma unroll
    for (int q = 0; q < 8; q++) {
      u32x4 w = *(const u32x4*)(&X2[t * 32 + ((q ^ r7) << 2)]);
      #pragma unroll
      for (int j = 0; j < 4; j++) {
        float2 xv = unpackh2(w[j]);
        int d = (q * 4 + j) * 2;
        a0 += xv.x * out_w[d] + xv.y * out_w[d + 1];
        a1 += xv.x * out_w[64 + d] + xv.y * out_w[64 + d + 1];
      }
    }
    *(float2*)(out + (size_t)(b * 1000 + t) * 2) = make_float2(a0, a1);
  }
}

extern "C" void kernel_launch(void* const* d_in, const int* in_sizes, int n_in,
                              void* d_out, int out_size, void* d_ws, size_t ws_size,
                              hipStream_t stream) {
  const int* tokens = (const int*)d_in[0];
  const float* emb = (const float*)d_in[1];
  const float* lin_w = (const float*)d_in[2];
  const float* lin_b = (const float*)d_in[3];
  const float* ff1_w = (const float*)d_in[4];
  const float* ff1_b = (const float*)d_in[5];
  const float* ff2_w = (const float*)d_in[6];
  const float* ff2_b = (const float*)d_in[7];
  const float* n1_g = (const float*)d_in[8];
  const float* n1_b = (const float*)d_in[9];
  const float* n2_g = (const float*)d_in[10];
  const float* n2_b = (const float*)d_in[11];
  const float* out_w = (const float*)d_in[12];
  const float* out_b = (const float*)d_in[13];
  float* out = (float*)d_out;

  f16* w1h = (f16*)d_ws;                         // 32 KiB
  f16* w2h = w1h + 16384;                        // 32 KiB
  float* petab = (float*)((char*)d_ws + 65536);  // 250 KiB (1000*64 f32)
  const size_t need = 65536 + 64000 * 4;
  const bool use_pe = (ws_size >= need);
  float* pe_arg = use_pe ? petab : nullptr;

  int pack_threads = 32768 + (use_pe ? 64000 : 0);
  int pack_blocks = (pack_threads + 255) / 256;
  pack_weights_kernel<<<pack_blocks, 256, 0, stream>>>(ff1_w, ff2_w, w1h, w2h, pe_arg);
  aat_kernel<<<512, TPB, 0, stream>>>(tokens, emb, lin_w, lin_b, ff1_b, ff2_b,
                                      n1_g, n1_b, n2_g, n2_b, out_w, out_b,
                                      w1h, w2h, pe_arg, out);
}

// Round 19
// 261.576 us; speedup vs baseline: 1.4285x; 1.0303x over previous
//
#include <hip/hip_runtime.h>
#include <stdint.h>

#define TPB 1024
#define NL 4

typedef _Float16 f16;
typedef _Float16 half2v __attribute__((ext_vector_type(2)));
typedef _Float16 f16x8 __attribute__((ext_vector_type(8)));
typedef float f32x4 __attribute__((ext_vector_type(4)));
typedef uint32_t u32x2 __attribute__((ext_vector_type(2)));
typedef uint32_t u32x4 __attribute__((ext_vector_type(4)));

// X2/Hb u32 index for row r, u32-col c: 16B-block XOR swizzle (block ^= r&7).
#define XIU(r, c) ((r) * 32 + (((((c) >> 2) ^ ((r) & 7))) << 2) + ((c) & 3))

static __device__ __forceinline__ uint32_t packh2(float a, float b) {
  half2v h;
  h.x = (_Float16)a;
  h.y = (_Float16)b;
  return __builtin_bit_cast(uint32_t, h);
}
static __device__ __forceinline__ float2 unpackh2(uint32_t u) {
  half2v h = __builtin_bit_cast(half2v, u);
  return make_float2((float)h.x, (float)h.y);
}
static __device__ __forceinline__ float fdot2h(uint32_t a, uint32_t b, float c) {
#if __has_builtin(__builtin_amdgcn_fdot2)
  return __builtin_amdgcn_fdot2(__builtin_bit_cast(half2v, a),
                                __builtin_bit_cast(half2v, b), c, false);
#else
  half2v x = __builtin_bit_cast(half2v, a);
  half2v y = __builtin_bit_cast(half2v, b);
  return c + (float)x.x * (float)y.x + (float)x.y * (float)y.y;
#endif
}

__global__ void pack_weights_kernel(const float* __restrict__ ff1_w,
                                    const float* __restrict__ ff2_w,
                                    f16* __restrict__ w1h,
                                    f16* __restrict__ w2h,
                                    float* __restrict__ petab) {
  int idx = blockIdx.x * blockDim.x + threadIdx.x;
  if (idx < 16384) {
    w1h[idx] = (f16)ff1_w[idx];
  } else if (idx < 32768) {
    w2h[idx - 16384] = (f16)ff2_w[idx - 16384];
  } else if (petab != nullptr && idx < 32768 + 64000) {
    int j = idx - 32768;
    int s = j >> 6, d = j & 63;
    float div = exp2f(-0.4152410118609203f * (float)(d >> 1));
    float ang = (float)s * div;
    petab[j] = (d & 1) ? cosf(ang) : sinf(ang);
  }
}

// R19 = R18 (200us) + three cuts inside the 64-VGPR discipline:
// 1. avg-combine + attn distributed over 256 threads (was wave0-serial ~1000
//    cyc while 15 waves idled): thread (o,q4) covers a 16-d quarter; coalesced
//    f32x4 lin_w loads; shfl_xor(1,2) combine; pair-pack via shfl_xor(4).
//    Costs one extra barrier.
// 2. saqa butterfly dropped: S_A/Q_A recomputed per-thread from the
//    already-loaded attnpk b128s via fdot2 (error ~1e-5 in mu, negligible).
// 3. LN1 normalize reads attn as f32x4: 16 loads instead of 32 b64.
__global__ __launch_bounds__(TPB) void aat_kernel(
    const int* __restrict__ tokens, const float* __restrict__ emb,
    const float* __restrict__ lin_w, const float* __restrict__ lin_b,
    const float* __restrict__ ff1_b, const float* __restrict__ ff2_b,
    const float* __restrict__ n1_g, const float* __restrict__ n1_b,
    const float* __restrict__ n2_g, const float* __restrict__ n2_b,
    const float* __restrict__ out_w, const float* __restrict__ out_b,
    const f16* __restrict__ w1h, const f16* __restrict__ w2h,
    const float* __restrict__ petab, float* __restrict__ out) {
  __shared__ __align__(16) uint32_t X2[1024 * 32];  // 131072 B
  __shared__ __align__(16) uint32_t Hb[2 * 4096];   // 32768 B: 2 H bufs / redbuf

  const int t = threadIdx.x;
  const int b = blockIdx.x;
  const int lane = t & 63;
  const int wv = t >> 6;                  // 0..15
  const bool valid = (t < 1000);
  float* redbuf = (float*)Hb;             // [32][64] f32 (avg phase)
  float* avgbuf = (float*)(Hb + 2048);    // 64 f32 (16B-aligned)
  float* attnbuf = (float*)(Hb + 2112);   // 64 f32 (16B-aligned)
  uint32_t* attnpk = Hb + 2176;           // 32 u32: attn as f16 pairs
  // (all die before FF's H buffers overwrite Hb)

  // ---------------- embed * sqrt(d) + positional encoding -> X2 ----------------
  if (valid) {
    int tok = tokens[b * 1000 + t];
    const float4* ev = (const float4*)(emb + (size_t)tok * 64);
    const int r7 = t & 7;
    if (petab != nullptr) {
      const float4* pv = (const float4*)(petab + (size_t)t * 64);
      #pragma unroll
      for (int q = 0; q < 8; q++) {
        float4 v0 = ev[2 * q], v1 = ev[2 * q + 1];
        float4 p0 = pv[2 * q], p1 = pv[2 * q + 1];
        u32x4 w;
        w[0] = packh2(fmaf(v0.x, 8.f, p0.x), fmaf(v0.y, 8.f, p0.y));
        w[1] = packh2(fmaf(v0.z, 8.f, p0.z), fmaf(v0.w, 8.f, p0.w));
        w[2] = packh2(fmaf(v1.x, 8.f, p1.x), fmaf(v1.y, 8.f, p1.y));
        w[3] = packh2(fmaf(v1.z, 8.f, p1.z), fmaf(v1.w, 8.f, p1.w));
        *(u32x4*)(&X2[t * 32 + ((q ^ r7) << 2)]) = w;
      }
    } else {
      float fs = (float)t;
      #pragma unroll
      for (int q = 0; q < 8; q++) {
        float4 v0 = ev[2 * q], v1 = ev[2 * q + 1];
        float d0 = exp2f(-0.4152410118609203f * (float)(4 * q));
        float d1 = exp2f(-0.4152410118609203f * (float)(4 * q + 1));
        float d2 = exp2f(-0.4152410118609203f * (float)(4 * q + 2));
        float d3 = exp2f(-0.4152410118609203f * (float)(4 * q + 3));
        u32x4 w;
        w[0] = packh2(fmaf(v0.x, 8.f, sinf(fs * d0)), fmaf(v0.y, 8.f, cosf(fs * d0)));
        w[1] = packh2(fmaf(v0.z, 8.f, sinf(fs * d1)), fmaf(v0.w, 8.f, cosf(fs * d1)));
        w[2] = packh2(fmaf(v1.x, 8.f, sinf(fs * d2)), fmaf(v1.y, 8.f, cosf(fs * d2)));
        w[3] = packh2(fmaf(v1.z, 8.f, sinf(fs * d3)), fmaf(v1.w, 8.f, cosf(fs * d3)));
        *(u32x4*)(&X2[t * 32 + ((q ^ r7) << 2)]) = w;
      }
    }
  } else {
    #pragma unroll
    for (int c = 0; c < 32; c += 4)
      *(u32x4*)(&X2[t * 32 + c]) = (u32x4){0u, 0u, 0u, 0u};  // pad rows zero
  }
  __syncthreads();

  const int l15 = lane & 15;
  const int g4 = lane >> 4;               // 0..3
  const int e7 = l15 & 7;                 // (row)&7 for all FF rows of this lane
  const int nt = wv & 3;                  // output-tile (16 cols of W1/W2)
  const int mr = wv >> 2;                 // row-group within a 128-row chunk
  const int cw = 8 * nt + 2 * g4;         // u32-col base of this lane's 4 outputs
  const int cswz = (((cw >> 2) ^ e7) << 2) + (cw & 3);  // swizzled col offset
  const uint32_t ONESPK = 0x3C003C00u;    // f16 pair (1.0, 1.0)

  #pragma unroll 1
  for (int l = 0; l < NL; l++) {
    const float* n1g = n1_g + l * 64;
    const float* n1b = n1_b + l * 64;
    const float* n2gl = n2_g + l * 64;
    const float* n2bl = n2_b + l * 64;

    // Per-wave weight tile (LICM hoists to layer scope: 24 VGPRs, fits)
    const f16* w1p = w1h + l * 4096 + (16 * nt + l15) * 64 + 8 * g4;
    f16x8 A10 = *(const f16x8*)(w1p);
    f16x8 A11 = *(const f16x8*)(w1p + 32);
    const f16* w2p = w2h + l * 4096 + (16 * nt + l15) * 64 + 8 * g4;
    f16x8 A20 = *(const f16x8*)(w2p);
    f16x8 A21 = *(const f16x8*)(w2p + 32);
    f32x4 bias1 = *(const f32x4*)(ff1_b + l * 64 + 16 * nt + 4 * g4);
    f32x4 bias2 = *(const f32x4*)(ff2_b + l * 64 + 16 * nt + 4 * g4);

    // ------- avg over sequence: column-parallel partials into redbuf -------
    {
      int cp = t & 31, rg = t >> 5;
      float s0 = 0.f, s1 = 0.f;
      for (int r = rg; r < 1000; r += 32) {
        float2 v = unpackh2(X2[XIU(r, cp)]);
        s0 += v.x;
        s1 += v.y;
      }
      redbuf[rg * 64 + 2 * cp] = s0;
      redbuf[rg * 64 + 2 * cp + 1] = s1;
    }
    __syncthreads();                       // bar 1: redbuf complete
    // ------- avg-combine distributed: 256 threads, (ch = t>>2, q4 = t&3) -------
    if (t < 256) {
      const int ch = t >> 2, q4 = t & 3;
      float s = 0.f;
      #pragma unroll
      for (int w = 0; w < 8; w++) s += redbuf[(q4 * 8 + w) * 64 + ch];
      s += __shfl_xor(s, 1, 64);
      s += __shfl_xor(s, 2, 64);
      if (q4 == 0) avgbuf[ch] = s * 1e-3f;
    }
    __syncthreads();                       // bar 1.5: avgbuf complete
    // ------- attn distributed: 256 threads, (o = t>>2, q4 = t&3) -------
    if (t < 256) {
      const int o = t >> 2, q4 = t & 3;
      const float* wr = lin_w + (size_t)(l * 64 + o) * 64 + 16 * q4;
      const f32x4* av4 = (const f32x4*)(avgbuf + 16 * q4);
      float a = 0.f;
      #pragma unroll
      for (int k = 0; k < 4; k++) {
        f32x4 wv4 = *(const f32x4*)(wr + 4 * k);
        f32x4 ag = av4[k];
        a += ag[0] * wv4[0] + ag[1] * wv4[1] + ag[2] * wv4[2] + ag[3] * wv4[3];
      }
      a += __shfl_xor(a, 1, 64);
      a += __shfl_xor(a, 2, 64);
      a += (q4 == 0) ? lin_b[l * 64 + o] : 0.f;
      // lane q4==0 of each o holds attn[o] (+bias); share bias-included value
      a = __shfl(a, (lane >> 2) << 2, 64);
      if (q4 == 0) attnbuf[o] = a;
      float pr = __shfl_xor(a, 4, 64);     // attn[o^1]
      if ((t & 7) == 0) attnpk[o >> 1] = packh2(a, pr);
    }
    __syncthreads();                       // bar 2: attn visible to all

    // ------- LN1 (thread t = row t): fdot2 stats + streaming normalize -------
    if (valid) {
      const int r7 = t & 7;
      float sx = 0.f, sxx = 0.f, sxa = 0.f, sA = 0.f, qA = 0.f;
      #pragma unroll
      for (int q = 0; q < 8; q++) {
        u32x4 w = *(const u32x4*)(&X2[t * 32 + ((q ^ r7) << 2)]);
        u32x4 ap = *(const u32x4*)(&attnpk[q * 4]);
        #pragma unroll
        for (int j = 0; j < 4; j++) {
          sx = fdot2h(w[j], ONESPK, sx);
          sxx = fdot2h(w[j], w[j], sxx);
          sxa = fdot2h(w[j], ap[j], sxa);
          sA = fdot2h(ap[j], ONESPK, sA);
          qA = fdot2h(ap[j], ap[j], qA);
        }
      }
      float m0 = sx + sA;
      float q0 = sxx + 2.f * sxa + qA;
      float mu = m0 * (1.0f / 64.0f);
      float var = q0 * (1.0f / 64.0f) - mu * mu;
      float rs = rsqrtf(var + 1e-5f);
      const f32x4* at4 = (const f32x4*)attnbuf;
      #pragma unroll
      for (int q = 0; q < 8; q++) {
        u32x4 w = *(const u32x4*)(&X2[t * 32 + ((q ^ r7) << 2)]);
        f32x4 aA = at4[2 * q];
        f32x4 aB = at4[2 * q + 1];
        u32x4 o;
        #pragma unroll
        for (int j = 0; j < 4; j++) {
          float2 xv = unpackh2(w[j]);
          float atx = (j < 2) ? aA[(j & 1) * 2] : aB[(j & 1) * 2];
          float aty = (j < 2) ? aA[(j & 1) * 2 + 1] : aB[(j & 1) * 2 + 1];
          int d = (q * 4 + j) * 2;
          float a0 = xv.x + atx, a1 = xv.y + aty;
          o[j] = packh2(fmaf((a0 - mu) * rs, n1g[d], n1b[d]),
                        fmaf((a1 - mu) * rs, n1g[d + 1], n1b[d + 1]));
        }
        *(u32x4*)(&X2[t * 32 + ((q ^ r7) << 2)]) = o;
      }
    }
    __syncthreads();                       // bar 3: Y visible to FF waves

    // ------- FF: 8 chunks of 128 rows, software-pipelined (dual H bufs) -------
#define MM1C(C, HB) { _Pragma("unroll") for (int sb = 0; sb < 2; sb++) { \
    const int s = 128 * (C) + 32 * mr + 16 * sb + l15; \
    u32x4 b0 = *(const u32x4*)(&X2[s * 32 + ((g4 ^ e7) << 2)]); \
    u32x4 b1 = *(const u32x4*)(&X2[s * 32 + (((4 + g4) ^ e7) << 2)]); \
    f32x4 acc = bias1; \
    acc = __builtin_amdgcn_mfma_f32_16x16x32_f16(A10, __builtin_bit_cast(f16x8, b0), acc, 0, 0, 0); \
    acc = __builtin_amdgcn_mfma_f32_16x16x32_f16(A11, __builtin_bit_cast(f16x8, b1), acc, 0, 0, 0); \
    const int hr = 32 * mr + 16 * sb + l15; \
    u32x2 hp; \
    hp[0] = packh2(fmaxf(acc[0], 0.f), fmaxf(acc[1], 0.f)); \
    hp[1] = packh2(fmaxf(acc[2], 0.f), fmaxf(acc[3], 0.f)); \
    *(u32x2*)(&(HB)[hr * 32 + cswz]) = hp; } }

#define MM2C(C, HB) { _Pragma("unroll") for (int sb = 0; sb < 2; sb++) { \
    const int s = 128 * (C) + 32 * mr + 16 * sb + l15; \
    const int hr = 32 * mr + 16 * sb + l15; \
    u32x4 h0 = *(const u32x4*)(&(HB)[hr * 32 + ((g4 ^ e7) << 2)]); \
    u32x4 h1 = *(const u32x4*)(&(HB)[hr * 32 + (((4 + g4) ^ e7) << 2)]); \
    u32x2 ry = *(const u32x2*)(&X2[s * 32 + cswz]); \
    float2 r0 = unpackh2(ry[0]), r1 = unpackh2(ry[1]); \
    f32x4 acc = bias2; \
    acc[0] += r0.x; acc[1] += r0.y; acc[2] += r1.x; acc[3] += r1.y; \
    acc = __builtin_amdgcn_mfma_f32_16x16x32_f16(A20, __builtin_bit_cast(f16x8, h0), acc, 0, 0, 0); \
    acc = __builtin_amdgcn_mfma_f32_16x16x32_f16(A21, __builtin_bit_cast(f16x8, h1), acc, 0, 0, 0); \
    u32x2 tw; \
    tw[0] = packh2(acc[0], acc[1]); \
    tw[1] = packh2(acc[2], acc[3]); \
    *(u32x2*)(&X2[s * 32 + cswz]) = tw; } }

    MM1C(0, Hb)
    __syncthreads();
    #pragma unroll 1
    for (int c = 1; c < 8; c++) {
      uint32_t* cur = Hb + ((c & 1) << 12);
      uint32_t* prv = Hb + (((c - 1) & 1) << 12);
      MM1C(c, cur)
      __builtin_amdgcn_sched_barrier(0);
      MM2C(c - 1, prv)
      __syncthreads();
    }
    MM2C(7, Hb + 4096)
    __syncthreads();
#undef MM1C
#undef MM2C

    // ------- LN2 (thread-per-row): fdot2 stats + streaming normalize -------
    if (valid) {
      const int r7 = t & 7;
      float m0 = 0.f, q0 = 0.f;
      #pragma unroll
      for (int q = 0; q < 8; q++) {
        u32x4 w = *(const u32x4*)(&X2[t * 32 + ((q ^ r7) << 2)]);
        #pragma unroll
        for (int j = 0; j < 4; j++) {
          m0 = fdot2h(w[j], ONESPK, m0);
          q0 = fdot2h(w[j], w[j], q0);
        }
      }
      float mu2 = m0 * (1.0f / 64.0f);
      float var2 = q0 * (1.0f / 64.0f) - mu2 * mu2;
      float rs2 = rsqrtf(var2 + 1e-5f);
      #pragma unroll
      for (int q = 0; q < 8; q++) {
        u32x4 w = *(const u32x4*)(&X2[t * 32 + ((q ^ r7) << 2)]);
        u32x4 o;
        #pragma unroll
        for (int j = 0; j < 4; j++) {
          float2 tv = unpackh2(w[j]);
          int d = (q * 4 + j) * 2;
          o[j] = packh2(fmaf((tv.x - mu2) * rs2, n2gl[d], n2bl[d]),
                        fmaf((tv.y - mu2) * rs2, n2gl[d + 1], n2bl[d + 1]));
        }
        *(u32x4*)(&X2[t * 32 + ((q ^ r7) << 2)]) = o;
      }
    } else {
      #pragma unroll
      for (int c = 0; c < 32; c += 4)
        *(u32x4*)(&X2[t * 32 + c]) = (u32x4){0u, 0u, 0u, 0u};  // re-zero pads
    }
    __syncthreads();                       // layer complete
  }

  // ---------------- output projection [B,S,2] ----------------
  if (valid) {
    const int r7 = t & 7;
    float a0 = out_b[0], a1 = out_b[1];
    #pragma unroll
    for (int q = 0; q < 8; q++) {
      u32x4 w = *(const u32x4*)(&X2[t * 32 + ((q ^ r7) << 2)]);
      #pragma unroll
      for (int j = 0; j < 4; j++) {
        float2 xv = unpackh2(w[j]);
        int d = (q * 4 + j) * 2;
        a0 += xv.x * out_w[d] + xv.y * out_w[d + 1];
        a1 += xv.x * out_w[64 + d] + xv.y * out_w[64 + d + 1];
      }
    }
    *(float2*)(out + (size_t)(b * 1000 + t) * 2) = make_float2(a0, a1);
  }
}

extern "C" void kernel_launch(void* const* d_in, const int* in_sizes, int n_in,
                              void* d_out, int out_size, void* d_ws, size_t ws_size,
                              hipStream_t stream) {
  const int* tokens = (const int*)d_in[0];
  const float* emb = (const float*)d_in[1];
  const float* lin_w = (const float*)d_in[2];
  const float* lin_b = (const float*)d_in[3];
  const float* ff1_w = (const float*)d_in[4];
  const float* ff1_b = (const float*)d_in[5];
  const float* ff2_w = (const float*)d_in[6];
  const float* ff2_b = (const float*)d_in[7];
  const float* n1_g = (const float*)d_in[8];
  const float* n1_b = (const float*)d_in[9];
  const float* n2_g = (const float*)d_in[10];
  const float* n2_b = (const float*)d_in[11];
  const float* out_w = (const float*)d_in[12];
  const float* out_b = (const float*)d_in[13];
  float* out = (float*)d_out;

  f16* w1h = (f16*)d_ws;                         // 32 KiB
  f16* w2h = w1h + 16384;                        // 32 KiB
  float* petab = (float*)((char*)d_ws + 65536);  // 250 KiB (1000*64 f32)
  const size_t need = 65536 + 64000 * 4;
  const bool use_pe = (ws_size >= need);
  float* pe_arg = use_pe ? petab : nullptr;

  int pack_threads = 32768 + (use_pe ? 64000 : 0);
  int pack_blocks = (pack_threads + 255) / 256;
  pack_weights_kernel<<<pack_blocks, 256, 0, stream>>>(ff1_w, ff2_w, w1h, w2h, pe_arg);
  aat_kernel<<<512, TPB, 0, stream>>>(tokens, emb, lin_w, lin_b, ff1_b, ff2_b,
                                      n1_g, n1_b, n2_g, n2_b, out_w, out_b,
                                      w1h, w2h, pe_arg, out);
}

// Round 20
// 258.903 us; speedup vs baseline: 1.4432x; 1.0103x over previous
//
#include <hip/hip_runtime.h>
#include <stdint.h>

#define TPB 1024
#define NL 4

typedef _Float16 f16;
typedef _Float16 half2v __attribute__((ext_vector_type(2)));
typedef _Float16 f16x8 __attribute__((ext_vector_type(8)));
typedef float f32x4 __attribute__((ext_vector_type(4)));
typedef uint32_t u32x2 __attribute__((ext_vector_type(2)));
typedef uint32_t u32x4 __attribute__((ext_vector_type(4)));

// X2/Hb u32 index for row r, u32-col c: 16B-block XOR swizzle (block ^= r&7).
#define XIU(r, c) ((r) * 32 + (((((c) >> 2) ^ ((r) & 7))) << 2) + ((c) & 3))

static __device__ __forceinline__ uint32_t packh2(float a, float b) {
  half2v h;
  h.x = (_Float16)a;
  h.y = (_Float16)b;
  return __builtin_bit_cast(uint32_t, h);
}
static __device__ __forceinline__ float2 unpackh2(uint32_t u) {
  half2v h = __builtin_bit_cast(half2v, u);
  return make_float2((float)h.x, (float)h.y);
}
static __device__ __forceinline__ float fdot2h(uint32_t a, uint32_t b, float c) {
#if __has_builtin(__builtin_amdgcn_fdot2)
  return __builtin_amdgcn_fdot2(__builtin_bit_cast(half2v, a),
                                __builtin_bit_cast(half2v, b), c, false);
#else
  half2v x = __builtin_bit_cast(half2v, a);
  half2v y = __builtin_bit_cast(half2v, b);
  return c + (float)x.x * (float)y.x + (float)x.y * (float)y.y;
#endif
}
// Load 8 consecutive f32 weights and convert to an f16x8 MFMA A-fragment
// (same rounding as the old pack kernel's (f16) cast).
static __device__ __forceinline__ f16x8 loadw8(const float* __restrict__ p) {
  f32x4 a = *(const f32x4*)p;
  f32x4 bq = *(const f32x4*)(p + 4);
  f16x8 r;
  r[0] = (f16)a[0];
  r[1] = (f16)a[1];
  r[2] = (f16)a[2];
  r[3] = (f16)a[3];
  r[4] = (f16)bq[0];
  r[5] = (f16)bq[1];
  r[6] = (f16)bq[2];
  r[7] = (f16)bq[3];
  return r;
}

// R20 = R19 (194us kernel) + single-launch: the bench's dur_us carried a
// stable ~67us gap over the aat dispatch (pack_weights launch + dispatch
// overhead). pack_weights is deleted: weights are read f32 and converted to
// f16 A-frags inline at the per-layer tile load (8 f32x4 + 32 cvt per wave
// per layer, L2-resident); PE is computed inline in embed via sinf/cosf
// (identical formula to the old petab fill, executed once, ~2us/block).
__global__ __launch_bounds__(TPB) void aat_kernel(
    const int* __restrict__ tokens, const float* __restrict__ emb,
    const float* __restrict__ lin_w, const float* __restrict__ lin_b,
    const float* __restrict__ ff1_w, const float* __restrict__ ff1_b,
    const float* __restrict__ ff2_w, const float* __restrict__ ff2_b,
    const float* __restrict__ n1_g, const float* __restrict__ n1_b,
    const float* __restrict__ n2_g, const float* __restrict__ n2_b,
    const float* __restrict__ out_w, const float* __restrict__ out_b,
    float* __restrict__ out) {
  __shared__ __align__(16) uint32_t X2[1024 * 32];  // 131072 B
  __shared__ __align__(16) uint32_t Hb[2 * 4096];   // 32768 B: 2 H bufs / redbuf

  const int t = threadIdx.x;
  const int b = blockIdx.x;
  const int lane = t & 63;
  const int wv = t >> 6;                  // 0..15
  const bool valid = (t < 1000);
  float* redbuf = (float*)Hb;             // [32][64] f32 (avg phase)
  float* avgbuf = (float*)(Hb + 2048);    // 64 f32 (16B-aligned)
  float* attnbuf = (float*)(Hb + 2112);   // 64 f32 (16B-aligned)
  uint32_t* attnpk = Hb + 2176;           // 32 u32: attn as f16 pairs
  // (all die before FF's H buffers overwrite Hb)

  // ---------------- embed * sqrt(d) + positional encoding -> X2 ----------------
  if (valid) {
    int tok = tokens[b * 1000 + t];
    const float4* ev = (const float4*)(emb + (size_t)tok * 64);
    const int r7 = t & 7;
    float fs = (float)t;
    #pragma unroll
    for (int q = 0; q < 8; q++) {
      float4 v0 = ev[2 * q], v1 = ev[2 * q + 1];
      // div_i = 10000^(-i/32) = exp2(-log2(10000)/32 * i), i = d>>1
      float d0 = exp2f(-0.4152410118609203f * (float)(4 * q));
      float d1 = exp2f(-0.4152410118609203f * (float)(4 * q + 1));
      float d2 = exp2f(-0.4152410118609203f * (float)(4 * q + 2));
      float d3 = exp2f(-0.4152410118609203f * (float)(4 * q + 3));
      u32x4 w;
      w[0] = packh2(fmaf(v0.x, 8.f, sinf(fs * d0)), fmaf(v0.y, 8.f, cosf(fs * d0)));
      w[1] = packh2(fmaf(v0.z, 8.f, sinf(fs * d1)), fmaf(v0.w, 8.f, cosf(fs * d1)));
      w[2] = packh2(fmaf(v1.x, 8.f, sinf(fs * d2)), fmaf(v1.y, 8.f, cosf(fs * d2)));
      w[3] = packh2(fmaf(v1.z, 8.f, sinf(fs * d3)), fmaf(v1.w, 8.f, cosf(fs * d3)));
      *(u32x4*)(&X2[t * 32 + ((q ^ r7) << 2)]) = w;
    }
  } else {
    #pragma unroll
    for (int c = 0; c < 32; c += 4)
      *(u32x4*)(&X2[t * 32 + c]) = (u32x4){0u, 0u, 0u, 0u};  // pad rows zero
  }
  __syncthreads();

  const int l15 = lane & 15;
  const int g4 = lane >> 4;               // 0..3
  const int e7 = l15 & 7;                 // (row)&7 for all FF rows of this lane
  const int nt = wv & 3;                  // output-tile (16 cols of W1/W2)
  const int mr = wv >> 2;                 // row-group within a 128-row chunk
  const int cw = 8 * nt + 2 * g4;         // u32-col base of this lane's 4 outputs
  const int cswz = (((cw >> 2) ^ e7) << 2) + (cw & 3);  // swizzled col offset
  const uint32_t ONESPK = 0x3C003C00u;    // f16 pair (1.0, 1.0)

  #pragma unroll 1
  for (int l = 0; l < NL; l++) {
    const float* n1g = n1_g + l * 64;
    const float* n1b = n1_b + l * 64;
    const float* n2gl = n2_g + l * 64;
    const float* n2bl = n2_b + l * 64;

    // Per-wave weight tile, f32 -> f16 inline (LICM hoists to layer scope)
    const float* w1p = ff1_w + (size_t)l * 4096 + (16 * nt + l15) * 64 + 8 * g4;
    f16x8 A10 = loadw8(w1p);
    f16x8 A11 = loadw8(w1p + 32);
    const float* w2p = ff2_w + (size_t)l * 4096 + (16 * nt + l15) * 64 + 8 * g4;
    f16x8 A20 = loadw8(w2p);
    f16x8 A21 = loadw8(w2p + 32);
    f32x4 bias1 = *(const f32x4*)(ff1_b + l * 64 + 16 * nt + 4 * g4);
    f32x4 bias2 = *(const f32x4*)(ff2_b + l * 64 + 16 * nt + 4 * g4);

    // ------- avg over sequence: column-parallel partials into redbuf -------
    {
      int cp = t & 31, rg = t >> 5;
      float s0 = 0.f, s1 = 0.f;
      for (int r = rg; r < 1000; r += 32) {
        float2 v = unpackh2(X2[XIU(r, cp)]);
        s0 += v.x;
        s1 += v.y;
      }
      redbuf[rg * 64 + 2 * cp] = s0;
      redbuf[rg * 64 + 2 * cp + 1] = s1;
    }
    __syncthreads();                       // bar 1: redbuf complete
    // ------- avg-combine distributed: 256 threads, (ch = t>>2, q4 = t&3) -------
    if (t < 256) {
      const int ch = t >> 2, q4 = t & 3;
      float s = 0.f;
      #pragma unroll
      for (int w = 0; w < 8; w++) s += redbuf[(q4 * 8 + w) * 64 + ch];
      s += __shfl_xor(s, 1, 64);
      s += __shfl_xor(s, 2, 64);
      if (q4 == 0) avgbuf[ch] = s * 1e-3f;
    }
    __syncthreads();                       // bar 1.5: avgbuf complete
    // ------- attn distributed: 256 threads, (o = t>>2, q4 = t&3) -------
    if (t < 256) {
      const int o = t >> 2, q4 = t & 3;
      const float* wr = lin_w + (size_t)(l * 64 + o) * 64 + 16 * q4;
      const f32x4* av4 = (const f32x4*)(avgbuf + 16 * q4);
      float a = 0.f;
      #pragma unroll
      for (int k = 0; k < 4; k++) {
        f32x4 wv4 = *(const f32x4*)(wr + 4 * k);
        f32x4 ag = av4[k];
        a += ag[0] * wv4[0] + ag[1] * wv4[1] + ag[2] * wv4[2] + ag[3] * wv4[3];
      }
      a += __shfl_xor(a, 1, 64);
      a += __shfl_xor(a, 2, 64);
      a += (q4 == 0) ? lin_b[l * 64 + o] : 0.f;
      // lane q4==0 of each o holds attn[o] (+bias); share bias-included value
      a = __shfl(a, (lane >> 2) << 2, 64);
      if (q4 == 0) attnbuf[o] = a;
      float pr = __shfl_xor(a, 4, 64);     // attn[o^1]
      if ((t & 7) == 0) attnpk[o >> 1] = packh2(a, pr);
    }
    __syncthreads();                       // bar 2: attn visible to all

    // ------- LN1 (thread t = row t): fdot2 stats + streaming normalize -------
    if (valid) {
      const int r7 = t & 7;
      float sx = 0.f, sxx = 0.f, sxa = 0.f, sA = 0.f, qA = 0.f;
      #pragma unroll
      for (int q = 0; q < 8; q++) {
        u32x4 w = *(const u32x4*)(&X2[t * 32 + ((q ^ r7) << 2)]);
        u32x4 ap = *(const u32x4*)(&attnpk[q * 4]);
        #pragma unroll
        for (int j = 0; j < 4; j++) {
          sx = fdot2h(w[j], ONESPK, sx);
          sxx = fdot2h(w[j], w[j], sxx);
          sxa = fdot2h(w[j], ap[j], sxa);
          sA = fdot2h(ap[j], ONESPK, sA);
          qA = fdot2h(ap[j], ap[j], qA);
        }
      }
      float m0 = sx + sA;
      float q0 = sxx + 2.f * sxa + qA;
      float mu = m0 * (1.0f / 64.0f);
      float var = q0 * (1.0f / 64.0f) - mu * mu;
      float rs = rsqrtf(var + 1e-5f);
      const f32x4* at4 = (const f32x4*)attnbuf;
      #pragma unroll
      for (int q = 0; q < 8; q++) {
        u32x4 w = *(const u32x4*)(&X2[t * 32 + ((q ^ r7) << 2)]);
        f32x4 aA = at4[2 * q];
        f32x4 aB = at4[2 * q + 1];
        u32x4 o;
        #pragma unroll
        for (int j = 0; j < 4; j++) {
          float2 xv = unpackh2(w[j]);
          float atx = (j < 2) ? aA[(j & 1) * 2] : aB[(j & 1) * 2];
          float aty = (j < 2) ? aA[(j & 1) * 2 + 1] : aB[(j & 1) * 2 + 1];
          int d = (q * 4 + j) * 2;
          float a0 = xv.x + atx, a1 = xv.y + aty;
          o[j] = packh2(fmaf((a0 - mu) * rs, n1g[d], n1b[d]),
                        fmaf((a1 - mu) * rs, n1g[d + 1], n1b[d + 1]));
        }
        *(u32x4*)(&X2[t * 32 + ((q ^ r7) << 2)]) = o;
      }
    }
    __syncthreads();                       // bar 3: Y visible to FF waves

    // ------- FF: 8 chunks of 128 rows, software-pipelined (dual H bufs) -------
#define MM1C(C, HB) { _Pragma("unroll") for (int sb = 0; sb < 2; sb++) { \
    const int s = 128 * (C) + 32 * mr + 16 * sb + l15; \
    u32x4 b0 = *(const u32x4*)(&X2[s * 32 + ((g4 ^ e7) << 2)]); \
    u32x4 b1 = *(const u32x4*)(&X2[s * 32 + (((4 + g4) ^ e7) << 2)]); \
    f32x4 acc = bias1; \
    acc = __builtin_amdgcn_mfma_f32_16x16x32_f16(A10, __builtin_bit_cast(f16x8, b0), acc, 0, 0, 0); \
    acc = __builtin_amdgcn_mfma_f32_16x16x32_f16(A11, __builtin_bit_cast(f16x8, b1), acc, 0, 0, 0); \
    const int hr = 32 * mr + 16 * sb + l15; \
    u32x2 hp; \
    hp[0] = packh2(fmaxf(acc[0], 0.f), fmaxf(acc[1], 0.f)); \
    hp[1] = packh2(fmaxf(acc[2], 0.f), fmaxf(acc[3], 0.f)); \
    *(u32x2*)(&(HB)[hr * 32 + cswz]) = hp; } }

#define MM2C(C, HB) { _Pragma("unroll") for (int sb = 0; sb < 2; sb++) { \
    const int s = 128 * (C) + 32 * mr + 16 * sb + l15; \
    const int hr = 32 * mr + 16 * sb + l15; \
    u32x4 h0 = *(const u32x4*)(&(HB)[hr * 32 + ((g4 ^ e7) << 2)]); \
    u32x4 h1 = *(const u32x4*)(&(HB)[hr * 32 + (((4 + g4) ^ e7) << 2)]); \
    u32x2 ry = *(const u32x2*)(&X2[s * 32 + cswz]); \
    float2 r0 = unpackh2(ry[0]), r1 = unpackh2(ry[1]); \
    f32x4 acc = bias2; \
    acc[0] += r0.x; acc[1] += r0.y; acc[2] += r1.x; acc[3] += r1.y; \
    acc = __builtin_amdgcn_mfma_f32_16x16x32_f16(A20, __builtin_bit_cast(f16x8, h0), acc, 0, 0, 0); \
    acc = __builtin_amdgcn_mfma_f32_16x16x32_f16(A21, __builtin_bit_cast(f16x8, h1), acc, 0, 0, 0); \
    u32x2 tw; \
    tw[0] = packh2(acc[0], acc[1]); \
    tw[1] = packh2(acc[2], acc[3]); \
    *(u32x2*)(&X2[s * 32 + cswz]) = tw; } }

    MM1C(0, Hb)
    __syncthreads();
    #pragma unroll 1
    for (int c = 1; c < 8; c++) {
      uint32_t* cur = Hb + ((c & 1) << 12);
      uint32_t* prv = Hb + (((c - 1) & 1) << 12);
      MM1C(c, cur)
      __builtin_amdgcn_sched_barrier(0);
      MM2C(c - 1, prv)
      __syncthreads();
    }
    MM2C(7, Hb + 4096)
    __syncthreads();
#undef MM1C
#undef MM2C

    // ------- LN2 (thread-per-row): fdot2 stats + streaming normalize -------
    if (valid) {
      const int r7 = t & 7;
      float m0 = 0.f, q0 = 0.f;
      #pragma unroll
      for (int q = 0; q < 8; q++) {
        u32x4 w = *(const u32x4*)(&X2[t * 32 + ((q ^ r7) << 2)]);
        #pragma unroll
        for (int j = 0; j < 4; j++) {
          m0 = fdot2h(w[j], ONESPK, m0);
          q0 = fdot2h(w[j], w[j], q0);
        }
      }
      float mu2 = m0 * (1.0f / 64.0f);
      float var2 = q0 * (1.0f / 64.0f) - mu2 * mu2;
      float rs2 = rsqrtf(var2 + 1e-5f);
      #pragma unroll
      for (int q = 0; q < 8; q++) {
        u32x4 w = *(const u32x4*)(&X2[t * 32 + ((q ^ r7) << 2)]);
        u32x4 o;
        #pragma unroll
        for (int j = 0; j < 4; j++) {
          float2 tv = unpackh2(w[j]);
          int d = (q * 4 + j) * 2;
          o[j] = packh2(fmaf((tv.x - mu2) * rs2, n2gl[d], n2bl[d]),
                        fmaf((tv.y - mu2) * rs2, n2gl[d + 1], n2bl[d + 1]));
        }
        *(u32x4*)(&X2[t * 32 + ((q ^ r7) << 2)]) = o;
      }
    } else {
      #pragma unroll
      for (int c = 0; c < 32; c += 4)
        *(u32x4*)(&X2[t * 32 + c]) = (u32x4){0u, 0u, 0u, 0u};  // re-zero pads
    }
    __syncthreads();                       // layer complete
  }

  // ---------------- output projection [B,S,2] ----------------
  if (valid) {
    const int r7 = t & 7;
    float a0 = out_b[0], a1 = out_b[1];
    #pragma unroll
    for (int q = 0; q < 8; q++) {
      u32x4 w = *(const u32x4*)(&X2[t * 32 + ((q ^ r7) << 2)]);
      #pragma unroll
      for (int j = 0; j < 4; j++) {
        float2 xv = unpackh2(w[j]);
        int d = (q * 4 + j) * 2;
        a0 += xv.x * out_w[d] + xv.y * out_w[d + 1];
        a1 += xv.x * out_w[64 + d] + xv.y * out_w[64 + d + 1];
      }
    }
    *(float2*)(out + (size_t)(b * 1000 + t) * 2) = make_float2(a0, a1);
  }
}

extern "C" void kernel_launch(void* const* d_in, const int* in_sizes, int n_in,
                              void* d_out, int out_size, void* d_ws, size_t ws_size,
                              hipStream_t stream) {
  const int* tokens = (const int*)d_in[0];
  const float* emb = (const float*)d_in[1];
  const float* lin_w = (const float*)d_in[2];
  const float* lin_b = (const float*)d_in[3];
  const float* ff1_w = (const float*)d_in[4];
  const float* ff1_b = (const float*)d_in[5];
  const float* ff2_w = (const float*)d_in[6];
  const float* ff2_b = (const float*)d_in[7];
  const float* n1_g = (const float*)d_in[8];
  const float* n1_b = (const float*)d_in[9];
  const float* n2_g = (const float*)d_in[10];
  const float* n2_b = (const float*)d_in[11];
  const float* out_w = (const float*)d_in[12];
  const float* out_b = (const float*)d_in[13];
  float* out = (float*)d_out;

  // Single launch: weight f32->f16 conversion and PE trig are inlined.
  aat_kernel<<<512, TPB, 0, stream>>>(tokens, emb, lin_w, lin_b, ff1_w, ff1_b,
                                      ff2_w, ff2_b, n1_g, n1_b, n2_g, n2_b,
                                      out_w, out_b, out);
}